// Round 2
// baseline (693.192 us; speedup 1.0000x reference)
//
#include <hip/hip_runtime.h>
#include <hip/hip_bf16.h>

// GCN 2-layer: out = gcn(relu(gcn(x,W1,b1)), W2, b2)
// gcn(x,W,b) = D^-1/2 (A+I) D^-1/2 (xW) + b, deg by dst (+1 self loop)
// Strategy: build CSR (by dst) each call -> atomic-free per-node aggregation.
// NOTE: harness passes integer inputs as int32 (not int64 as in the JAX ref).

#define FIN 256
#define HDIM 128
#define CDIM 40

__global__ __launch_bounds__(256) void zero_int_k(int* p, int n) {
    int i = blockIdx.x * 256 + threadIdx.x;
    if (i < n) p[i] = 0;
}

__global__ __launch_bounds__(256) void count_deg_k(const int* __restrict__ ei,
                                                   int* __restrict__ deg, int E) {
    int e = blockIdx.x * 256 + threadIdx.x;
    if (e >= E) return;
    int d = ei[E + e];   // dst row
    atomicAdd(&deg[d], 1);
}

__global__ __launch_bounds__(256) void block_sums_k(const int* __restrict__ deg,
                                                    int* __restrict__ part, int N) {
    __shared__ int sm[256];
    int i = blockIdx.x * 256 + threadIdx.x;
    sm[threadIdx.x] = (i < N) ? deg[i] : 0;
    __syncthreads();
    for (int d = 128; d > 0; d >>= 1) {
        if (threadIdx.x < d) sm[threadIdx.x] += sm[threadIdx.x + d];
        __syncthreads();
    }
    if (threadIdx.x == 0) part[blockIdx.x] = sm[0];
}

// single-block exclusive scan of nb (<=512) partials
__global__ __launch_bounds__(512) void scan_part_k(int* part, int nb) {
    __shared__ int sm[512];
    int t = threadIdx.x;
    int v = (t < nb) ? part[t] : 0;
    sm[t] = v;
    __syncthreads();
    for (int d = 1; d < 512; d <<= 1) {
        int tv = (t >= d) ? sm[t - d] : 0;
        __syncthreads();
        sm[t] += tv;
        __syncthreads();
    }
    if (t < nb) part[t] = sm[t] - v;   // exclusive
}

__global__ __launch_bounds__(256) void scan_final_k(const int* __restrict__ deg,
                                                    const int* __restrict__ part,
                                                    int* __restrict__ offs, int* __restrict__ cur,
                                                    float* __restrict__ dinv, float* __restrict__ invd,
                                                    int N, int E) {
    __shared__ int sm[256];
    int tid = threadIdx.x;
    int i = blockIdx.x * 256 + tid;
    int v = (i < N) ? deg[i] : 0;
    sm[tid] = v;
    __syncthreads();
    for (int d = 1; d < 256; d <<= 1) {
        int tv = (tid >= d) ? sm[tid - d] : 0;
        __syncthreads();
        sm[tid] += tv;
        __syncthreads();
    }
    if (i < N) {
        int incl = sm[tid];
        int base = part[blockIdx.x];
        int o = base + (incl - v);
        offs[i] = o;
        cur[i] = o;
        float dg = (float)(v + 1);
        dinv[i] = rsqrtf(dg);
        invd[i] = 1.0f / dg;
        if (i == N - 1) offs[N] = base + incl;  // == E
    }
}

__global__ __launch_bounds__(256) void fill_csr_k(const int* __restrict__ ei,
                                                  int* __restrict__ cur, int* __restrict__ csr, int E) {
    int e = blockIdx.x * 256 + threadIdx.x;
    if (e >= E) return;
    int s = ei[e];
    int d = ei[E + e];
    int p = atomicAdd(&cur[d], 1);
    csr[p] = s;
}

// GEMM1: T = X(Nx256) @ W(256x128). 64x128 tile, 256 thr, 4x8/thread.
__global__ __launch_bounds__(256) void gemm1_k(const float* __restrict__ X, const float* __restrict__ W,
                                               float* __restrict__ T, int N) {
    __shared__ float As[16][64];    // As[k][r]
    __shared__ float Bs[16][128];
    const int tid = threadIdx.x;
    const int tx = tid & 15;        // col group: cols tx*4..+3 and 64+tx*4..+3
    const int ty = tid >> 4;        // row group: rows ty*4..+3
    const int rowbase = blockIdx.x * 64;
    const int ar = tid >> 2;        // 0..63 (A load row)
    const int ak = (tid & 3) * 4;   // 0,4,8,12
    const int arow = min(rowbase + ar, N - 1);
    const float* xrow = X + (size_t)arow * FIN + ak;

    float acc[4][8];
#pragma unroll
    for (int i = 0; i < 4; i++)
#pragma unroll
        for (int j = 0; j < 8; j++) acc[i][j] = 0.0f;

    for (int k0 = 0; k0 < FIN; k0 += 16) {
        float4 a4 = *(const float4*)(xrow + k0);
        int idx = tid * 2;
        int br0 = idx >> 5, bc0 = (idx & 31) * 4;
        float4 b4a = *(const float4*)(W + (size_t)(k0 + br0) * HDIM + bc0);
        idx++;
        int br1 = idx >> 5, bc1 = (idx & 31) * 4;
        float4 b4b = *(const float4*)(W + (size_t)(k0 + br1) * HDIM + bc1);

        As[ak + 0][ar] = a4.x; As[ak + 1][ar] = a4.y;
        As[ak + 2][ar] = a4.z; As[ak + 3][ar] = a4.w;
        *(float4*)&Bs[br0][bc0] = b4a;
        *(float4*)&Bs[br1][bc1] = b4b;
        __syncthreads();

#pragma unroll
        for (int kk = 0; kk < 16; ++kk) {
            float4 av  = *(const float4*)&As[kk][ty * 4];
            float4 bv0 = *(const float4*)&Bs[kk][tx * 4];
            float4 bv1 = *(const float4*)&Bs[kk][64 + tx * 4];
            float a[4] = {av.x, av.y, av.z, av.w};
            float b[8] = {bv0.x, bv0.y, bv0.z, bv0.w, bv1.x, bv1.y, bv1.z, bv1.w};
#pragma unroll
            for (int i = 0; i < 4; i++)
#pragma unroll
                for (int j = 0; j < 8; j++) acc[i][j] += a[i] * b[j];
        }
        __syncthreads();
    }
#pragma unroll
    for (int i = 0; i < 4; i++) {
        int r = rowbase + ty * 4 + i;
        if (r < N) {
            float4 v0 = {acc[i][0], acc[i][1], acc[i][2], acc[i][3]};
            float4 v1 = {acc[i][4], acc[i][5], acc[i][6], acc[i][7]};
            *(float4*)(T + (size_t)r * HDIM + tx * 4) = v0;
            *(float4*)(T + (size_t)r * HDIM + 64 + tx * 4) = v1;
        }
    }
}

// agg1: per-node gather + self loop + bias + relu. block = 128 (one node).
__global__ __launch_bounds__(128) void agg1_k(const float* __restrict__ T1, const int* __restrict__ offs,
                                              const int* __restrict__ csr, const float* __restrict__ dinv,
                                              const float* __restrict__ invd, const float* __restrict__ b1,
                                              float* __restrict__ H, int N) {
    int i = blockIdx.x;
    int f = threadIdx.x;
    float di = dinv[i];
    float acc = T1[(size_t)i * HDIM + f] * invd[i] + b1[f];
    int e0 = offs[i], e1 = offs[i + 1];
    for (int e = e0; e < e1; ++e) {
        int s = csr[e];
        acc += (dinv[s] * di) * T1[(size_t)s * HDIM + f];
    }
    H[(size_t)i * HDIM + f] = fmaxf(acc, 0.0f);
}

// GEMM2: T = H(Nx128) @ W2(128x40). 128-row tile, 256 thr, 4x5/thread.
__global__ __launch_bounds__(256) void gemm2_k(const float* __restrict__ Hm, const float* __restrict__ W,
                                               float* __restrict__ T, int N) {
    __shared__ float As[32][128];   // As[k][r]
    __shared__ float Bs[32][40];
    const int tid = threadIdx.x;
    const int ct = tid & 7;         // cols ct*5..+4
    const int rt = tid >> 3;        // rows rt*4..+3
    const int rowbase = blockIdx.x * 128;
    float acc[4][5];
#pragma unroll
    for (int i = 0; i < 4; i++)
#pragma unroll
        for (int j = 0; j < 5; j++) acc[i][j] = 0.0f;

    for (int k0 = 0; k0 < HDIM; k0 += 32) {
#pragma unroll
        for (int l = 0; l < 4; ++l) {
            int idx = tid + l * 256;
            int r = idx >> 3;           // 0..127
            int kc = (idx & 7) * 4;     // 0..28
            int gr = min(rowbase + r, N - 1);
            float4 v = *(const float4*)(Hm + (size_t)gr * HDIM + k0 + kc);
            As[kc + 0][r] = v.x; As[kc + 1][r] = v.y;
            As[kc + 2][r] = v.z; As[kc + 3][r] = v.w;
        }
#pragma unroll
        for (int l = 0; l < 5; ++l) {
            int idx = tid + l * 256;    // 0..1279
            Bs[idx / 40][idx % 40] = W[k0 * 40 + idx];
        }
        __syncthreads();
#pragma unroll
        for (int kk = 0; kk < 32; ++kk) {
            float4 av = *(const float4*)&As[kk][rt * 4];
            float a[4] = {av.x, av.y, av.z, av.w};
            float b[5];
#pragma unroll
            for (int j = 0; j < 5; j++) b[j] = Bs[kk][ct * 5 + j];
#pragma unroll
            for (int i = 0; i < 4; i++)
#pragma unroll
                for (int j = 0; j < 5; j++) acc[i][j] += a[i] * b[j];
        }
        __syncthreads();
    }
#pragma unroll
    for (int i = 0; i < 4; i++) {
        int r = rowbase + rt * 4 + i;
        if (r < N) {
#pragma unroll
            for (int j = 0; j < 5; j++) T[(size_t)r * CDIM + ct * 5 + j] = acc[i][j];
        }
    }
}

// agg2: per-node gather + self loop + bias -> d_out. one wave per node.
__global__ __launch_bounds__(64) void agg2_k(const float* __restrict__ T2, const int* __restrict__ offs,
                                             const int* __restrict__ csr, const float* __restrict__ dinv,
                                             const float* __restrict__ invd, const float* __restrict__ b2,
                                             float* __restrict__ OUT, int N) {
    int i = blockIdx.x;
    int c = threadIdx.x;
    if (c >= CDIM) return;
    float di = dinv[i];
    float acc = T2[(size_t)i * CDIM + c] * invd[i] + b2[c];
    int e0 = offs[i], e1 = offs[i + 1];
    for (int e = e0; e < e1; ++e) {
        int s = csr[e];
        acc += (dinv[s] * di) * T2[(size_t)s * CDIM + c];
    }
    OUT[(size_t)i * CDIM + c] = acc;
}

extern "C" void kernel_launch(void* const* d_in, const int* in_sizes, int n_in,
                              void* d_out, int out_size, void* d_ws, size_t ws_size,
                              hipStream_t stream) {
    const float* x   = (const float*)d_in[0];
    const int*   ei  = (const int*)d_in[1];     // int32! (harness converts int64 -> int32)
    const float* W1  = (const float*)d_in[2];
    const float* b1  = (const float*)d_in[3];
    const float* W2  = (const float*)d_in[4];
    const float* b2  = (const float*)d_in[5];
    float*       out = (float*)d_out;

    const int Hd  = in_sizes[3];            // 128
    const int Fin = in_sizes[2] / Hd;       // 256
    const int N   = in_sizes[0] / Fin;      // 100000
    const int E   = in_sizes[1] / 2;        // 1600000

    // workspace layout
    char* base = (char*)d_ws;
    size_t off = 0;
    auto alloc = [&](size_t bytes) -> void* {
        void* p = base + off;
        off += (bytes + 255) & ~(size_t)255;
        return p;
    };
    int*   deg  = (int*)alloc((size_t)N * 4);
    int*   offs = (int*)alloc(((size_t)N + 1) * 4);
    int*   cur  = (int*)alloc((size_t)N * 4);
    float* dinv = (float*)alloc((size_t)N * 4);
    float* invd = (float*)alloc((size_t)N * 4);
    int*   part = (int*)alloc(512 * 4);
    int*   csr  = (int*)alloc((size_t)E * 4);
    float* t1   = (float*)alloc((size_t)N * HDIM * 4);
    float* h    = (float*)alloc((size_t)N * HDIM * 4);
    float* t2   = t1;   // t1 dead after agg1; reuse for t2 (N x 40)

    const int nb = (N + 255) / 256;   // 391 <= 512

    zero_int_k<<<(N + 255) / 256, 256, 0, stream>>>(deg, N);
    count_deg_k<<<(E + 255) / 256, 256, 0, stream>>>(ei, deg, E);
    block_sums_k<<<nb, 256, 0, stream>>>(deg, part, N);
    scan_part_k<<<1, 512, 0, stream>>>(part, nb);
    scan_final_k<<<nb, 256, 0, stream>>>(deg, part, offs, cur, dinv, invd, N, E);
    fill_csr_k<<<(E + 255) / 256, 256, 0, stream>>>(ei, cur, csr, E);

    gemm1_k<<<(N + 63) / 64, 256, 0, stream>>>(x, W1, t1, N);
    agg1_k<<<N, 128, 0, stream>>>(t1, offs, csr, dinv, invd, b1, h, N);
    gemm2_k<<<(N + 127) / 128, 256, 0, stream>>>(h, W2, t2, N);
    agg2_k<<<N, 64, 0, stream>>>(t2, offs, csr, dinv, invd, b2, out, N);
}

// Round 3
// 506.266 us; speedup vs baseline: 1.3692x; 1.3692x over previous
//
#include <hip/hip_runtime.h>
#include <hip/hip_bf16.h>

// GCN 2-layer: out = gcn(relu(gcn(x,W1,b1)), W2, b2)
// gcn(x,W,b) = D^-1/2 (A+I) D^-1/2 (xW) + b
// R3: t1 in bf16 (halves agg1 gather bytes), gemm1 via bf16 MFMA,
//     agg kernels: wave/node + register neighbor cache + 4x unrolled gathers.

#define FIN 256
#define HDIM 128
#define CDIM 40

typedef __attribute__((ext_vector_type(8))) short bf16x8;
typedef __attribute__((ext_vector_type(4))) float f32x4;

__device__ inline short f2bf(float f) {               // RNE fp32 -> bf16
    unsigned u = __float_as_uint(f);
    unsigned r = (u + 0x7FFFu + ((u >> 16) & 1u)) >> 16;
    return (short)r;
}
__device__ inline float bflo(unsigned u) { return __uint_as_float(u << 16); }
__device__ inline float bfhi(unsigned u) { return __uint_as_float(u & 0xFFFF0000u); }

__global__ __launch_bounds__(256) void zero_int_k(int* p, int n) {
    int i = blockIdx.x * 256 + threadIdx.x;
    if (i < n) p[i] = 0;
}

__global__ __launch_bounds__(256) void count_deg_k(const int* __restrict__ ei,
                                                   int* __restrict__ deg, int E) {
    int e = blockIdx.x * 256 + threadIdx.x;
    if (e >= E) return;
    atomicAdd(&deg[ei[E + e]], 1);
}

__global__ __launch_bounds__(256) void block_sums_k(const int* __restrict__ deg,
                                                    int* __restrict__ part, int N) {
    __shared__ int sm[256];
    int i = blockIdx.x * 256 + threadIdx.x;
    sm[threadIdx.x] = (i < N) ? deg[i] : 0;
    __syncthreads();
    for (int d = 128; d > 0; d >>= 1) {
        if (threadIdx.x < d) sm[threadIdx.x] += sm[threadIdx.x + d];
        __syncthreads();
    }
    if (threadIdx.x == 0) part[blockIdx.x] = sm[0];
}

__global__ __launch_bounds__(512) void scan_part_k(int* part, int nb) {
    __shared__ int sm[512];
    int t = threadIdx.x;
    int v = (t < nb) ? part[t] : 0;
    sm[t] = v;
    __syncthreads();
    for (int d = 1; d < 512; d <<= 1) {
        int tv = (t >= d) ? sm[t - d] : 0;
        __syncthreads();
        sm[t] += tv;
        __syncthreads();
    }
    if (t < nb) part[t] = sm[t] - v;
}

__global__ __launch_bounds__(256) void scan_final_k(const int* __restrict__ deg,
                                                    const int* __restrict__ part,
                                                    int* __restrict__ offs, int* __restrict__ cur,
                                                    float* __restrict__ dinv, float* __restrict__ invd,
                                                    int N, int E) {
    __shared__ int sm[256];
    int tid = threadIdx.x;
    int i = blockIdx.x * 256 + tid;
    int v = (i < N) ? deg[i] : 0;
    sm[tid] = v;
    __syncthreads();
    for (int d = 1; d < 256; d <<= 1) {
        int tv = (tid >= d) ? sm[tid - d] : 0;
        __syncthreads();
        sm[tid] += tv;
        __syncthreads();
    }
    if (i < N) {
        int incl = sm[tid];
        int base = part[blockIdx.x];
        int o = base + (incl - v);
        offs[i] = o;
        cur[i] = o;
        float dg = (float)(v + 1);
        dinv[i] = rsqrtf(dg);
        invd[i] = 1.0f / dg;
        if (i == N - 1) offs[N] = base + incl;
    }
}

__global__ __launch_bounds__(256) void fill_csr_k(const int* __restrict__ ei,
                                                  int* __restrict__ cur, int* __restrict__ csr,
                                                  float* __restrict__ csrw, const float* __restrict__ dinv,
                                                  int E) {
    int e = blockIdx.x * 256 + threadIdx.x;
    if (e >= E) return;
    int s = ei[e];
    int d = ei[E + e];
    int p = atomicAdd(&cur[d], 1);
    csr[p] = s;
    csrw[p] = dinv[s];
}

// cast+transpose W1[256][128] fp32 -> W1T[128][256] bf16
__global__ __launch_bounds__(256) void castW1_k(const float* __restrict__ W1, short* __restrict__ W1T) {
    int idx = blockIdx.x * 256 + threadIdx.x;     // 32768
    int k = idx >> 7, n = idx & 127;
    W1T[n * FIN + k] = f2bf(W1[idx]);
}

// GEMM1 (MFMA bf16): T1b = bf16( X(Nx256) @ W1(256x128) ).
// 128x128 block tile, 4 waves 2x2, each wave 64x64 via 4x4 of 16x16x32.
#define LDSTRIDE 40   // 32 k + 8 pad (bf16 elems); 80 B row keeps b128 reads ~2-way
__global__ __launch_bounds__(256) void gemm1_mfma_k(const float* __restrict__ X,
                                                    const short* __restrict__ W1T,
                                                    short* __restrict__ T1b, int N) {
    __shared__ short As[128 * LDSTRIDE];   // [m][k]
    __shared__ short Bs[128 * LDSTRIDE];   // [n][k]
    const int tid = threadIdx.x;
    const int lane = tid & 63;
    const int wid = tid >> 6;
    const int w0 = wid & 1, w1 = wid >> 1;
    const int quad = lane >> 4;
    const int l16 = lane & 15;
    const int rowbase = blockIdx.x * 128;
    const int sr = tid >> 1;     // staging row 0..127
    const int sh = tid & 1;      // k half (16 elems)

    f32x4 acc[4][4];
#pragma unroll
    for (int a = 0; a < 4; a++)
#pragma unroll
        for (int b = 0; b < 4; b++) acc[a][b] = (f32x4){0.f, 0.f, 0.f, 0.f};

    const int arow = min(rowbase + sr, N - 1);
    const float* xsrc = X + (size_t)arow * FIN + sh * 16;
    const int4* bsrc = (const int4*)(W1T + (size_t)sr * FIN + sh * 16);

    for (int k0 = 0; k0 < FIN; k0 += 32) {
        // stage A (fp32 -> bf16)
        float vals[16];
        *(float4*)&vals[0]  = *(const float4*)(xsrc + k0);
        *(float4*)&vals[4]  = *(const float4*)(xsrc + k0 + 4);
        *(float4*)&vals[8]  = *(const float4*)(xsrc + k0 + 8);
        *(float4*)&vals[12] = *(const float4*)(xsrc + k0 + 12);
        short tmp[16];
#pragma unroll
        for (int c = 0; c < 16; c++) tmp[c] = f2bf(vals[c]);
        ((int4*)&As[sr * LDSTRIDE + sh * 16])[0] = ((int4*)tmp)[0];
        ((int4*)&As[sr * LDSTRIDE + sh * 16])[1] = ((int4*)tmp)[1];
        // stage B (already bf16)
        int4 b0 = bsrc[k0 >> 3];       // (k0+sh*16) elems -> /8 int4 units from row start
        int4 b1 = bsrc[(k0 >> 3) + 1];
        ((int4*)&Bs[sr * LDSTRIDE + sh * 16])[0] = b0;
        ((int4*)&Bs[sr * LDSTRIDE + sh * 16])[1] = b1;
        __syncthreads();

        bf16x8 afr[4], bfr[4];
#pragma unroll
        for (int mt = 0; mt < 4; mt++)
            afr[mt] = *(const bf16x8*)&As[(w1 * 64 + mt * 16 + l16) * LDSTRIDE + quad * 8];
#pragma unroll
        for (int nt = 0; nt < 4; nt++)
            bfr[nt] = *(const bf16x8*)&Bs[(w0 * 64 + nt * 16 + l16) * LDSTRIDE + quad * 8];
#pragma unroll
        for (int mt = 0; mt < 4; mt++)
#pragma unroll
            for (int nt = 0; nt < 4; nt++)
                acc[mt][nt] = __builtin_amdgcn_mfma_f32_16x16x32_bf16(afr[mt], bfr[nt], acc[mt][nt], 0, 0, 0);
        __syncthreads();
    }
    // epilogue: D row = quad*4+r, col = l16 (within 16x16 tile)
#pragma unroll
    for (int mt = 0; mt < 4; mt++) {
#pragma unroll
        for (int r = 0; r < 4; r++) {
            int row = rowbase + w1 * 64 + mt * 16 + quad * 4 + r;
            if (row < N) {
#pragma unroll
                for (int nt = 0; nt < 4; nt++) {
                    int col = w0 * 64 + nt * 16 + l16;
                    T1b[(size_t)row * HDIM + col] = f2bf(acc[mt][nt][r]);
                }
            }
        }
    }
}

// agg1: wave per node. t1 bf16 rows (256B). Register neighbor cache + shfl + 4x unroll.
__global__ __launch_bounds__(256) void agg1_k(const short* __restrict__ T1b, const int* __restrict__ offs,
                                              const int* __restrict__ csr, const float* __restrict__ csrw,
                                              const float* __restrict__ dinv, const float* __restrict__ invd,
                                              const float* __restrict__ b1, float* __restrict__ H, int N) {
    const int lane = threadIdx.x & 63;
    const int i = blockIdx.x * 4 + (threadIdx.x >> 6);
    if (i >= N) return;
    const int e0 = offs[i], e1 = offs[i + 1];
    const int deg = e1 - e0;
    int sv = 0; float wv = 0.f;
    if (lane < deg) { sv = csr[e0 + lane]; wv = csrw[e0 + lane]; }

    float accx = 0.f, accy = 0.f;      // neighbor part (x di later)
    const int dmain = deg < 64 ? deg : 64;
    const int d4 = dmain & ~3;
    const unsigned* rowp = (const unsigned*)T1b;   // 2 bf16 per unsigned
    int j = 0;
    for (; j < d4; j += 4) {
        int s0 = __shfl(sv, j), s1 = __shfl(sv, j + 1), s2 = __shfl(sv, j + 2), s3 = __shfl(sv, j + 3);
        float w0 = __shfl(wv, j), w1 = __shfl(wv, j + 1), w2 = __shfl(wv, j + 2), w3 = __shfl(wv, j + 3);
        unsigned r0 = rowp[(size_t)s0 * 64 + lane];
        unsigned r1 = rowp[(size_t)s1 * 64 + lane];
        unsigned r2 = rowp[(size_t)s2 * 64 + lane];
        unsigned r3 = rowp[(size_t)s3 * 64 + lane];
        accx += w0 * bflo(r0) + w1 * bflo(r1) + w2 * bflo(r2) + w3 * bflo(r3);
        accy += w0 * bfhi(r0) + w1 * bfhi(r1) + w2 * bfhi(r2) + w3 * bfhi(r3);
    }
    for (; j < dmain; ++j) {
        int s = __shfl(sv, j); float w = __shfl(wv, j);
        unsigned r = rowp[(size_t)s * 64 + lane];
        accx += w * bflo(r); accy += w * bfhi(r);
    }
    for (int e = e0 + 64; e < e1; ++e) {     // rare tail (deg > 64)
        int s = csr[e]; float w = csrw[e];
        unsigned r = rowp[(size_t)s * 64 + lane];
        accx += w * bflo(r); accy += w * bfhi(r);
    }
    const float di = dinv[i], sf = invd[i];
    unsigned rs = rowp[(size_t)i * 64 + lane];
    float2 bc = *(const float2*)(b1 + 2 * lane);
    float ox = bc.x + sf * bflo(rs) + di * accx;
    float oy = bc.y + sf * bfhi(rs) + di * accy;
    float2 o = {fmaxf(ox, 0.f), fmaxf(oy, 0.f)};
    *(float2*)(H + (size_t)i * HDIM + 2 * lane) = o;
}

// GEMM2: T2 = H(Nx128) @ W2(128x40), fp32 vector ALU (small).
__global__ __launch_bounds__(256) void gemm2_k(const float* __restrict__ Hm, const float* __restrict__ W,
                                               float* __restrict__ T, int N) {
    __shared__ float As2[32][128];
    __shared__ float Bs2[32][40];
    const int tid = threadIdx.x;
    const int ct = tid & 7;
    const int rt = tid >> 3;
    const int rowbase = blockIdx.x * 128;
    float acc[4][5];
#pragma unroll
    for (int i = 0; i < 4; i++)
#pragma unroll
        for (int j = 0; j < 5; j++) acc[i][j] = 0.0f;

    for (int k0 = 0; k0 < HDIM; k0 += 32) {
#pragma unroll
        for (int l = 0; l < 4; ++l) {
            int idx = tid + l * 256;
            int r = idx >> 3;
            int kc = (idx & 7) * 4;
            int gr = min(rowbase + r, N - 1);
            float4 v = *(const float4*)(Hm + (size_t)gr * HDIM + k0 + kc);
            As2[kc + 0][r] = v.x; As2[kc + 1][r] = v.y;
            As2[kc + 2][r] = v.z; As2[kc + 3][r] = v.w;
        }
#pragma unroll
        for (int l = 0; l < 5; ++l) {
            int idx = tid + l * 256;
            Bs2[idx / 40][idx % 40] = W[k0 * 40 + idx];
        }
        __syncthreads();
#pragma unroll
        for (int kk = 0; kk < 32; ++kk) {
            float4 av = *(const float4*)&As2[kk][rt * 4];
            float a[4] = {av.x, av.y, av.z, av.w};
            float b[5];
#pragma unroll
            for (int j = 0; j < 5; j++) b[j] = Bs2[kk][ct * 5 + j];
#pragma unroll
            for (int i = 0; i < 4; i++)
#pragma unroll
                for (int j = 0; j < 5; j++) acc[i][j] += a[i] * b[j];
        }
        __syncthreads();
    }
#pragma unroll
    for (int i = 0; i < 4; i++) {
        int r = rowbase + rt * 4 + i;
        if (r < N) {
#pragma unroll
            for (int j = 0; j < 5; j++) T[(size_t)r * CDIM + ct * 5 + j] = acc[i][j];
        }
    }
}

// agg2: wave per node, fp32 t2 (160B rows). Same neighbor-cache structure.
__global__ __launch_bounds__(256) void agg2_k(const float* __restrict__ T2, const int* __restrict__ offs,
                                              const int* __restrict__ csr, const float* __restrict__ csrw,
                                              const float* __restrict__ dinv, const float* __restrict__ invd,
                                              const float* __restrict__ b2, float* __restrict__ OUT, int N) {
    const int lane = threadIdx.x & 63;
    const int i = blockIdx.x * 4 + (threadIdx.x >> 6);
    if (i >= N) return;
    const int e0 = offs[i], e1 = offs[i + 1];
    const int deg = e1 - e0;
    int sv = 0; float wv = 0.f;
    if (lane < deg) { sv = csr[e0 + lane]; wv = csrw[e0 + lane]; }
    const int c = lane < CDIM ? lane : CDIM - 1;   // clamp: lanes 40..63 share lane 39's line
    float accE = 0.f;
    const int dmain = deg < 64 ? deg : 64;
    const int d4 = dmain & ~3;
    int j = 0;
    for (; j < d4; j += 4) {
        int s0 = __shfl(sv, j), s1 = __shfl(sv, j + 1), s2 = __shfl(sv, j + 2), s3 = __shfl(sv, j + 3);
        float w0 = __shfl(wv, j), w1 = __shfl(wv, j + 1), w2 = __shfl(wv, j + 2), w3 = __shfl(wv, j + 3);
        float v0 = T2[(size_t)s0 * CDIM + c];
        float v1 = T2[(size_t)s1 * CDIM + c];
        float v2 = T2[(size_t)s2 * CDIM + c];
        float v3 = T2[(size_t)s3 * CDIM + c];
        accE += w0 * v0 + w1 * v1 + w2 * v2 + w3 * v3;
    }
    for (; j < dmain; ++j) {
        int s = __shfl(sv, j); float w = __shfl(wv, j);
        accE += w * T2[(size_t)s * CDIM + c];
    }
    for (int e = e0 + 64; e < e1; ++e) {
        int s = csr[e]; float w = csrw[e];
        accE += w * T2[(size_t)s * CDIM + c];
    }
    if (lane < CDIM)
        OUT[(size_t)i * CDIM + lane] = b2[lane] + invd[i] * T2[(size_t)i * CDIM + lane] + dinv[i] * accE;
}

extern "C" void kernel_launch(void* const* d_in, const int* in_sizes, int n_in,
                              void* d_out, int out_size, void* d_ws, size_t ws_size,
                              hipStream_t stream) {
    const float* x   = (const float*)d_in[0];
    const int*   ei  = (const int*)d_in[1];     // int32 in harness
    const float* W1  = (const float*)d_in[2];
    const float* b1  = (const float*)d_in[3];
    const float* W2  = (const float*)d_in[4];
    const float* b2  = (const float*)d_in[5];
    float*       out = (float*)d_out;

    const int Hd  = in_sizes[3];            // 128
    const int Fin = in_sizes[2] / Hd;       // 256
    const int N   = in_sizes[0] / Fin;      // 100000
    const int E   = in_sizes[1] / 2;        // 1600000

    char* base = (char*)d_ws;
    size_t off = 0;
    auto alloc = [&](size_t bytes) -> void* {
        void* p = base + off;
        off += (bytes + 255) & ~(size_t)255;
        return p;
    };
    int*   deg  = (int*)alloc((size_t)N * 4);
    int*   offs = (int*)alloc(((size_t)N + 1) * 4);
    int*   cur  = (int*)alloc((size_t)N * 4);
    float* dinv = (float*)alloc((size_t)N * 4);
    float* invd = (float*)alloc((size_t)N * 4);
    int*   part = (int*)alloc(512 * 4);
    int*   csr  = (int*)alloc((size_t)E * 4);
    float* csrw = (float*)alloc((size_t)E * 4);
    short* W1T  = (short*)alloc((size_t)HDIM * FIN * 2);
    short* t1b  = (short*)alloc((size_t)N * HDIM * 2);
    float* h    = (float*)alloc((size_t)N * HDIM * 4);
    float* t2   = (float*)alloc((size_t)N * CDIM * 4);

    const int nb = (N + 255) / 256;

    zero_int_k<<<(N + 255) / 256, 256, 0, stream>>>(deg, N);
    count_deg_k<<<(E + 255) / 256, 256, 0, stream>>>(ei, deg, E);
    block_sums_k<<<nb, 256, 0, stream>>>(deg, part, N);
    scan_part_k<<<1, 512, 0, stream>>>(part, nb);
    scan_final_k<<<nb, 256, 0, stream>>>(deg, part, offs, cur, dinv, invd, N, E);
    fill_csr_k<<<(E + 255) / 256, 256, 0, stream>>>(ei, cur, csr, csrw, dinv, E);
    castW1_k<<<(HDIM * Fin + 255) / 256, 256, 0, stream>>>(W1, W1T);

    gemm1_mfma_k<<<(N + 127) / 128, 256, 0, stream>>>(x, W1T, t1b, N);
    agg1_k<<<(N + 3) / 4, 256, 0, stream>>>(t1b, offs, csr, csrw, dinv, invd, b1, h, N);
    gemm2_k<<<(N + 127) / 128, 256, 0, stream>>>(h, W2, t2, N);
    agg2_k<<<(N + 3) / 4, 256, 0, stream>>>(t2, offs, csr, csrw, dinv, invd, b2, out, N);
}

// Round 4
// 394.494 us; speedup vs baseline: 1.7572x; 1.2833x over previous
//
#include <hip/hip_runtime.h>
#include <hip/hip_bf16.h>

// GCN 2-layer: out = gcn(relu(gcn(x,W1,b1)), W2, b2)
// R4: CSR build rewritten as 2-level counting sort (bucket = dst>>8).
//     No global atomics, all heavy writes coalesced. csrw dropped (agg fetches dinv[src]).

#define FIN 256
#define HDIM 128
#define CDIM 40
#define CAP 8192          // per-bucket edge capacity (mean 4096, Poisson tail ~0)
#define EC 2048           // edges per block in pass 1

typedef __attribute__((ext_vector_type(8))) short bf16x8;
typedef __attribute__((ext_vector_type(4))) float f32x4;

__device__ inline short f2bf(float f) {               // RNE fp32 -> bf16
    unsigned u = __float_as_uint(f);
    unsigned r = (u + 0x7FFFu + ((u >> 16) & 1u)) >> 16;
    return (short)r;
}
__device__ inline float bflo(unsigned u) { return __uint_as_float(u << 16); }
__device__ inline float bfhi(unsigned u) { return __uint_as_float(u & 0xFFFF0000u); }

// ---- pass 1a: per-block bucket histograms (no atomics to global) ----
__global__ __launch_bounds__(256) void p1_hist_k(const int* __restrict__ ei, int* __restrict__ mat,
                                                 int E, int NBUCK) {
    __shared__ int hist[512];
    for (int t = threadIdx.x; t < NBUCK; t += 256) hist[t] = 0;
    __syncthreads();
    int e0 = blockIdx.x * EC;
#pragma unroll
    for (int k = 0; k < EC; k += 256) {
        int e = e0 + k + threadIdx.x;
        if (e < E) atomicAdd(&hist[ei[E + e] >> 8], 1);
    }
    __syncthreads();
    for (int t = threadIdx.x; t < NBUCK; t += 256) mat[blockIdx.x * NBUCK + t] = hist[t];
}

// ---- pass 1b: column scan -> global write bases (in-place), bucket counts ----
__global__ __launch_bounds__(64) void scan_cols_k(int* __restrict__ mat, int* __restrict__ bcnt,
                                                  int NB1, int NBUCK) {
    int b = blockIdx.x;
    int lane = threadIdx.x;
    int carry = b * CAP;
    for (int c0 = 0; c0 < NB1; c0 += 64) {
        int idx = c0 + lane;
        int v = (idx < NB1) ? mat[idx * NBUCK + b] : 0;
        int incl = v;
#pragma unroll
        for (int off = 1; off < 64; off <<= 1) {
            int t = __shfl_up(incl, off);
            if (lane >= off) incl += t;
        }
        if (idx < NB1) mat[idx * NBUCK + b] = carry + (incl - v);
        carry += __shfl(incl, 63);
    }
    if (lane == 0) bcnt[b] = carry - b * CAP;
}

// ---- pass 1c: scatter packed records into bucket append regions ----
__global__ __launch_bounds__(256) void p1_scatter_k(const int* __restrict__ ei, const int* __restrict__ mat,
                                                    int* __restrict__ bmem, int E, int NBUCK) {
    __shared__ int base[512];
    for (int t = threadIdx.x; t < NBUCK; t += 256) base[t] = mat[blockIdx.x * NBUCK + t];
    __syncthreads();
    int e0 = blockIdx.x * EC;
#pragma unroll
    for (int k = 0; k < EC; k += 256) {
        int e = e0 + k + threadIdx.x;
        if (e < E) {
            int s = ei[e];
            int d = ei[E + e];
            int pos = atomicAdd(&base[d >> 8], 1);
            bmem[pos] = s | ((d & 255) << 20);    // s < 2^20 (N=100000)
        }
    }
}

// ---- pass 2: per-bucket CSR build, all global writes coalesced ----
__global__ __launch_bounds__(256) void p2_build_k(const int* __restrict__ bmem, const int* __restrict__ bcnt,
                                                  int* __restrict__ csr, int2* __restrict__ nseg,
                                                  float* __restrict__ dinv, float* __restrict__ invd, int N) {
    __shared__ int hist[256], cur[256], sc[256];
    __shared__ int stage[CAP];
    const int b = blockIdx.x;
    const int tid = threadIdx.x;
    int cnt = bcnt[b];
    if (cnt > CAP) cnt = CAP;
    const int* src = bmem + b * CAP;
    hist[tid] = 0;
    __syncthreads();
    for (int j = tid; j < cnt; j += 256) atomicAdd(&hist[src[j] >> 20], 1);
    __syncthreads();
    int v = hist[tid];
    sc[tid] = v;
    __syncthreads();
    for (int off = 1; off < 256; off <<= 1) {
        int t = (tid >= off) ? sc[tid - off] : 0;
        __syncthreads();
        sc[tid] += t;
        __syncthreads();
    }
    int excl = sc[tid] - v;
    cur[tid] = excl;
    int i = b * 256 + tid;
    if (i < N) {
        nseg[i] = make_int2(b * CAP + excl, v);
        float dg = (float)(v + 1);
        dinv[i] = rsqrtf(dg);
        invd[i] = 1.0f / dg;
    }
    __syncthreads();
    for (int j = tid; j < cnt; j += 256) {
        int rec = src[j];
        int pos = atomicAdd(&cur[rec >> 20], 1);
        stage[pos] = rec & 0xFFFFF;
    }
    __syncthreads();
    int* dst = csr + b * CAP;
    for (int j = tid; j < cnt; j += 256) dst[j] = stage[j];
}

// cast+transpose W1[256][128] fp32 -> W1T[128][256] bf16
__global__ __launch_bounds__(256) void castW1_k(const float* __restrict__ W1, short* __restrict__ W1T) {
    int idx = blockIdx.x * 256 + threadIdx.x;     // 32768
    int k = idx >> 7, n = idx & 127;
    W1T[n * FIN + k] = f2bf(W1[idx]);
}

// GEMM1 (MFMA bf16): T1b = bf16( X(Nx256) @ W1(256x128) ).
#define LDSTRIDE 40
__global__ __launch_bounds__(256) void gemm1_mfma_k(const float* __restrict__ X,
                                                    const short* __restrict__ W1T,
                                                    short* __restrict__ T1b, int N) {
    __shared__ short As[128 * LDSTRIDE];
    __shared__ short Bs[128 * LDSTRIDE];
    const int tid = threadIdx.x;
    const int lane = tid & 63;
    const int wid = tid >> 6;
    const int w0 = wid & 1, w1 = wid >> 1;
    const int quad = lane >> 4;
    const int l16 = lane & 15;
    const int rowbase = blockIdx.x * 128;
    const int sr = tid >> 1;
    const int sh = tid & 1;

    f32x4 acc[4][4];
#pragma unroll
    for (int a = 0; a < 4; a++)
#pragma unroll
        for (int b = 0; b < 4; b++) acc[a][b] = (f32x4){0.f, 0.f, 0.f, 0.f};

    const int arow = min(rowbase + sr, N - 1);
    const float* xsrc = X + (size_t)arow * FIN + sh * 16;
    const int4* bsrc = (const int4*)(W1T + (size_t)sr * FIN + sh * 16);

    for (int k0 = 0; k0 < FIN; k0 += 32) {
        float vals[16];
        *(float4*)&vals[0]  = *(const float4*)(xsrc + k0);
        *(float4*)&vals[4]  = *(const float4*)(xsrc + k0 + 4);
        *(float4*)&vals[8]  = *(const float4*)(xsrc + k0 + 8);
        *(float4*)&vals[12] = *(const float4*)(xsrc + k0 + 12);
        short tmp[16];
#pragma unroll
        for (int c = 0; c < 16; c++) tmp[c] = f2bf(vals[c]);
        ((int4*)&As[sr * LDSTRIDE + sh * 16])[0] = ((int4*)tmp)[0];
        ((int4*)&As[sr * LDSTRIDE + sh * 16])[1] = ((int4*)tmp)[1];
        int4 b0 = bsrc[k0 >> 3];
        int4 b1 = bsrc[(k0 >> 3) + 1];
        ((int4*)&Bs[sr * LDSTRIDE + sh * 16])[0] = b0;
        ((int4*)&Bs[sr * LDSTRIDE + sh * 16])[1] = b1;
        __syncthreads();

        bf16x8 afr[4], bfr[4];
#pragma unroll
        for (int mt = 0; mt < 4; mt++)
            afr[mt] = *(const bf16x8*)&As[(w1 * 64 + mt * 16 + l16) * LDSTRIDE + quad * 8];
#pragma unroll
        for (int nt = 0; nt < 4; nt++)
            bfr[nt] = *(const bf16x8*)&Bs[(w0 * 64 + nt * 16 + l16) * LDSTRIDE + quad * 8];
#pragma unroll
        for (int mt = 0; mt < 4; mt++)
#pragma unroll
            for (int nt = 0; nt < 4; nt++)
                acc[mt][nt] = __builtin_amdgcn_mfma_f32_16x16x32_bf16(afr[mt], bfr[nt], acc[mt][nt], 0, 0, 0);
        __syncthreads();
    }
#pragma unroll
    for (int mt = 0; mt < 4; mt++) {
#pragma unroll
        for (int r = 0; r < 4; r++) {
            int row = rowbase + w1 * 64 + mt * 16 + quad * 4 + r;
            if (row < N) {
#pragma unroll
                for (int nt = 0; nt < 4; nt++) {
                    int col = w0 * 64 + nt * 16 + l16;
                    T1b[(size_t)row * HDIM + col] = f2bf(acc[mt][nt][r]);
                }
            }
        }
    }
}

// agg1: wave per node. bf16 rows, register neighbor cache + shfl + 4x unroll.
__global__ __launch_bounds__(256) void agg1_k(const short* __restrict__ T1b, const int2* __restrict__ nseg,
                                              const int* __restrict__ csr, const float* __restrict__ dinv,
                                              const float* __restrict__ invd, const float* __restrict__ b1,
                                              float* __restrict__ H, int N) {
    const int lane = threadIdx.x & 63;
    const int i = blockIdx.x * 4 + (threadIdx.x >> 6);
    if (i >= N) return;
    const int2 sg = nseg[i];
    const int e0 = sg.x, deg = sg.y;
    int sv = 0; float wv = 0.f;
    if (lane < deg) { sv = csr[e0 + lane]; wv = dinv[sv]; }

    float accx = 0.f, accy = 0.f;
    const int dmain = deg < 64 ? deg : 64;
    const int d4 = dmain & ~3;
    const unsigned* rowp = (const unsigned*)T1b;
    int j = 0;
    for (; j < d4; j += 4) {
        int s0 = __shfl(sv, j), s1 = __shfl(sv, j + 1), s2 = __shfl(sv, j + 2), s3 = __shfl(sv, j + 3);
        float w0 = __shfl(wv, j), w1 = __shfl(wv, j + 1), w2 = __shfl(wv, j + 2), w3 = __shfl(wv, j + 3);
        unsigned r0 = rowp[(size_t)s0 * 64 + lane];
        unsigned r1 = rowp[(size_t)s1 * 64 + lane];
        unsigned r2 = rowp[(size_t)s2 * 64 + lane];
        unsigned r3 = rowp[(size_t)s3 * 64 + lane];
        accx += w0 * bflo(r0) + w1 * bflo(r1) + w2 * bflo(r2) + w3 * bflo(r3);
        accy += w0 * bfhi(r0) + w1 * bfhi(r1) + w2 * bfhi(r2) + w3 * bfhi(r3);
    }
    for (; j < dmain; ++j) {
        int s = __shfl(sv, j); float w = __shfl(wv, j);
        unsigned r = rowp[(size_t)s * 64 + lane];
        accx += w * bflo(r); accy += w * bfhi(r);
    }
    for (int e = e0 + 64; e < e0 + deg; ++e) {
        int s = csr[e]; float w = dinv[s];
        unsigned r = rowp[(size_t)s * 64 + lane];
        accx += w * bflo(r); accy += w * bfhi(r);
    }
    const float di = dinv[i], sf = invd[i];
    unsigned rs = rowp[(size_t)i * 64 + lane];
    float2 bc = *(const float2*)(b1 + 2 * lane);
    float ox = bc.x + sf * bflo(rs) + di * accx;
    float oy = bc.y + sf * bfhi(rs) + di * accy;
    float2 o = {fmaxf(ox, 0.f), fmaxf(oy, 0.f)};
    *(float2*)(H + (size_t)i * HDIM + 2 * lane) = o;
}

// GEMM2: T2 = H(Nx128) @ W2(128x40), fp32 vector ALU.
__global__ __launch_bounds__(256) void gemm2_k(const float* __restrict__ Hm, const float* __restrict__ W,
                                               float* __restrict__ T, int N) {
    __shared__ float As2[32][128];
    __shared__ float Bs2[32][40];
    const int tid = threadIdx.x;
    const int ct = tid & 7;
    const int rt = tid >> 3;
    const int rowbase = blockIdx.x * 128;
    float acc[4][5];
#pragma unroll
    for (int i = 0; i < 4; i++)
#pragma unroll
        for (int j = 0; j < 5; j++) acc[i][j] = 0.0f;

    for (int k0 = 0; k0 < HDIM; k0 += 32) {
#pragma unroll
        for (int l = 0; l < 4; ++l) {
            int idx = tid + l * 256;
            int r = idx >> 3;
            int kc = (idx & 7) * 4;
            int gr = min(rowbase + r, N - 1);
            float4 v = *(const float4*)(Hm + (size_t)gr * HDIM + k0 + kc);
            As2[kc + 0][r] = v.x; As2[kc + 1][r] = v.y;
            As2[kc + 2][r] = v.z; As2[kc + 3][r] = v.w;
        }
#pragma unroll
        for (int l = 0; l < 5; ++l) {
            int idx = tid + l * 256;
            Bs2[idx / 40][idx % 40] = W[k0 * 40 + idx];
        }
        __syncthreads();
#pragma unroll
        for (int kk = 0; kk < 32; ++kk) {
            float4 av = *(const float4*)&As2[kk][rt * 4];
            float a[4] = {av.x, av.y, av.z, av.w};
            float b[5];
#pragma unroll
            for (int j = 0; j < 5; j++) b[j] = Bs2[kk][ct * 5 + j];
#pragma unroll
            for (int i = 0; i < 4; i++)
#pragma unroll
                for (int j = 0; j < 5; j++) acc[i][j] += a[i] * b[j];
        }
        __syncthreads();
    }
#pragma unroll
    for (int i = 0; i < 4; i++) {
        int r = rowbase + rt * 4 + i;
        if (r < N) {
#pragma unroll
            for (int j = 0; j < 5; j++) T[(size_t)r * CDIM + ct * 5 + j] = acc[i][j];
        }
    }
}

// agg2: wave per node, fp32 t2 (160B rows).
__global__ __launch_bounds__(256) void agg2_k(const float* __restrict__ T2, const int2* __restrict__ nseg,
                                              const int* __restrict__ csr, const float* __restrict__ dinv,
                                              const float* __restrict__ invd, const float* __restrict__ b2,
                                              float* __restrict__ OUT, int N) {
    const int lane = threadIdx.x & 63;
    const int i = blockIdx.x * 4 + (threadIdx.x >> 6);
    if (i >= N) return;
    const int2 sg = nseg[i];
    const int e0 = sg.x, deg = sg.y;
    int sv = 0; float wv = 0.f;
    if (lane < deg) { sv = csr[e0 + lane]; wv = dinv[sv]; }
    const int c = lane < CDIM ? lane : CDIM - 1;
    float accE = 0.f;
    const int dmain = deg < 64 ? deg : 64;
    const int d4 = dmain & ~3;
    int j = 0;
    for (; j < d4; j += 4) {
        int s0 = __shfl(sv, j), s1 = __shfl(sv, j + 1), s2 = __shfl(sv, j + 2), s3 = __shfl(sv, j + 3);
        float w0 = __shfl(wv, j), w1 = __shfl(wv, j + 1), w2 = __shfl(wv, j + 2), w3 = __shfl(wv, j + 3);
        float v0 = T2[(size_t)s0 * CDIM + c];
        float v1 = T2[(size_t)s1 * CDIM + c];
        float v2 = T2[(size_t)s2 * CDIM + c];
        float v3 = T2[(size_t)s3 * CDIM + c];
        accE += w0 * v0 + w1 * v1 + w2 * v2 + w3 * v3;
    }
    for (; j < dmain; ++j) {
        int s = __shfl(sv, j); float w = __shfl(wv, j);
        accE += w * T2[(size_t)s * CDIM + c];
    }
    for (int e = e0 + 64; e < e0 + deg; ++e) {
        int s = csr[e]; float w = dinv[s];
        accE += w * T2[(size_t)s * CDIM + c];
    }
    if (lane < CDIM)
        OUT[(size_t)i * CDIM + lane] = b2[lane] + invd[i] * T2[(size_t)i * CDIM + lane] + dinv[i] * accE;
}

extern "C" void kernel_launch(void* const* d_in, const int* in_sizes, int n_in,
                              void* d_out, int out_size, void* d_ws, size_t ws_size,
                              hipStream_t stream) {
    const float* x   = (const float*)d_in[0];
    const int*   ei  = (const int*)d_in[1];     // int32 in harness
    const float* W1  = (const float*)d_in[2];
    const float* b1  = (const float*)d_in[3];
    const float* W2  = (const float*)d_in[4];
    const float* b2  = (const float*)d_in[5];
    float*       out = (float*)d_out;

    const int Hd  = in_sizes[3];            // 128
    const int Fin = in_sizes[2] / Hd;       // 256
    const int N   = in_sizes[0] / Fin;      // 100000
    const int E   = in_sizes[1] / 2;        // 1600000

    const int NBUCK = (N + 255) / 256;      // 391
    const int NB1   = (E + EC - 1) / EC;    // 782

    char* base = (char*)d_ws;
    size_t off = 0;
    auto alloc = [&](size_t bytes) -> void* {
        void* p = base + off;
        off += (bytes + 255) & ~(size_t)255;
        return p;
    };
    // region A: mat+bmem (pass1/2 only), overlaid later by t1b (gemm1 onward)
    size_t matB  = (size_t)NB1 * NBUCK * 4;
    size_t bmemB = (size_t)NBUCK * CAP * 4;
    size_t t1bB  = (size_t)N * HDIM * 2;
    size_t regA  = matB + 256 + bmemB;
    if (t1bB > regA) regA = t1bB;
    char* pA = (char*)alloc(regA);
    int*   mat  = (int*)pA;
    int*   bmem = (int*)(pA + ((matB + 255) & ~(size_t)255));
    short* t1b  = (short*)pA;

    int*   bcnt = (int*)alloc((size_t)NBUCK * 4);
    int*   csr  = (int*)alloc((size_t)NBUCK * CAP * 4);
    int2*  nseg = (int2*)alloc((size_t)N * 8);
    float* dinv = (float*)alloc((size_t)N * 4);
    float* invd = (float*)alloc((size_t)N * 4);
    short* W1T  = (short*)alloc((size_t)HDIM * FIN * 2);
    float* h    = (float*)alloc((size_t)N * HDIM * 4);
    float* t2   = (float*)alloc((size_t)N * CDIM * 4);

    p1_hist_k<<<NB1, 256, 0, stream>>>(ei, mat, E, NBUCK);
    scan_cols_k<<<NBUCK, 64, 0, stream>>>(mat, bcnt, NB1, NBUCK);
    p1_scatter_k<<<NB1, 256, 0, stream>>>(ei, mat, bmem, E, NBUCK);
    p2_build_k<<<NBUCK, 256, 0, stream>>>(bmem, bcnt, csr, nseg, dinv, invd, N);
    castW1_k<<<(HDIM * Fin + 255) / 256, 256, 0, stream>>>(W1, W1T);

    gemm1_mfma_k<<<(N + 127) / 128, 256, 0, stream>>>(x, W1T, t1b, N);
    agg1_k<<<(N + 3) / 4, 256, 0, stream>>>(t1b, nseg, csr, dinv, invd, b1, h, N);
    gemm2_k<<<(N + 127) / 128, 256, 0, stream>>>(h, W2, t2, N);
    agg2_k<<<(N + 3) / 4, 256, 0, stream>>>(t2, nseg, csr, dinv, invd, b2, out, N);
}

// Round 5
// 360.614 us; speedup vs baseline: 1.9223x; 1.0939x over previous
//
#include <hip/hip_runtime.h>
#include <hip/hip_bf16.h>

// GCN 2-layer. R5: readlane-based agg (saddr gathers, unroll 8), h stored bf16,
// gemm2 via bf16 MFMA (W2 padded 40->48 cols), p1 counting-sort blocks 4x bigger.

#define FIN 256
#define HDIM 128
#define CDIM 40
#define CAP 8192          // per-bucket edge capacity (mean 4096)
#define EC 8192           // edges per block in pass 1

typedef __attribute__((ext_vector_type(8))) short bf16x8;
typedef __attribute__((ext_vector_type(4))) float f32x4;

__device__ inline short f2bf(float f) {               // RNE fp32 -> bf16
    unsigned u = __float_as_uint(f);
    unsigned r = (u + 0x7FFFu + ((u >> 16) & 1u)) >> 16;
    return (short)r;
}
__device__ inline float bflo(unsigned u) { return __uint_as_float(u << 16); }
__device__ inline float bfhi(unsigned u) { return __uint_as_float(u & 0xFFFF0000u); }
__device__ inline int rdl_i(int v, int l) { return __builtin_amdgcn_readlane(v, l); }
__device__ inline float rdl_f(float v, int l) {
    return __uint_as_float((unsigned)__builtin_amdgcn_readlane((int)__float_as_uint(v), l));
}

// ---- pass 1a: per-block bucket histograms ----
__global__ __launch_bounds__(1024) void p1_hist_k(const int* __restrict__ ei, int* __restrict__ mat,
                                                  int E, int NBUCK) {
    __shared__ int hist[512];
    for (int t = threadIdx.x; t < NBUCK; t += 1024) hist[t] = 0;
    __syncthreads();
    int e0 = blockIdx.x * EC;
#pragma unroll
    for (int k = 0; k < EC; k += 1024) {
        int e = e0 + k + threadIdx.x;
        if (e < E) atomicAdd(&hist[ei[E + e] >> 8], 1);
    }
    __syncthreads();
    for (int t = threadIdx.x; t < NBUCK; t += 1024) mat[blockIdx.x * NBUCK + t] = hist[t];
}

// ---- pass 1b: column scan -> global write bases (in-place), bucket counts ----
__global__ __launch_bounds__(64) void scan_cols_k(int* __restrict__ mat, int* __restrict__ bcnt,
                                                  int NB1, int NBUCK) {
    int b = blockIdx.x;
    int lane = threadIdx.x;
    int carry = b * CAP;
    for (int c0 = 0; c0 < NB1; c0 += 64) {
        int idx = c0 + lane;
        int v = (idx < NB1) ? mat[idx * NBUCK + b] : 0;
        int incl = v;
#pragma unroll
        for (int off = 1; off < 64; off <<= 1) {
            int t = __shfl_up(incl, off);
            if (lane >= off) incl += t;
        }
        if (idx < NB1) mat[idx * NBUCK + b] = carry + (incl - v);
        carry += __shfl(incl, 63);
    }
    if (lane == 0) bcnt[b] = carry - b * CAP;
}

// ---- pass 1c: scatter packed records into bucket append regions ----
__global__ __launch_bounds__(1024) void p1_scatter_k(const int* __restrict__ ei, const int* __restrict__ mat,
                                                     int* __restrict__ bmem, int E, int NBUCK) {
    __shared__ int base[512];
    for (int t = threadIdx.x; t < NBUCK; t += 1024) base[t] = mat[blockIdx.x * NBUCK + t];
    __syncthreads();
    int e0 = blockIdx.x * EC;
#pragma unroll
    for (int k = 0; k < EC; k += 1024) {
        int e = e0 + k + threadIdx.x;
        if (e < E) {
            int s = ei[e];
            int d = ei[E + e];
            int pos = atomicAdd(&base[d >> 8], 1);
            bmem[pos] = s | ((d & 255) << 20);    // s < 2^20 (N=100000)
        }
    }
}

// ---- pass 2: per-bucket CSR build, coalesced writes ----
__global__ __launch_bounds__(256) void p2_build_k(const int* __restrict__ bmem, const int* __restrict__ bcnt,
                                                  int* __restrict__ csr, int2* __restrict__ nseg,
                                                  float* __restrict__ dinv, float* __restrict__ invd, int N) {
    __shared__ int hist[256], cur[256], sc[256];
    __shared__ int stage[CAP];
    const int b = blockIdx.x;
    const int tid = threadIdx.x;
    int cnt = bcnt[b];
    if (cnt > CAP) cnt = CAP;
    const int* src = bmem + b * CAP;
    hist[tid] = 0;
    __syncthreads();
    for (int j = tid; j < cnt; j += 256) atomicAdd(&hist[src[j] >> 20], 1);
    __syncthreads();
    int v = hist[tid];
    sc[tid] = v;
    __syncthreads();
    for (int off = 1; off < 256; off <<= 1) {
        int t = (tid >= off) ? sc[tid - off] : 0;
        __syncthreads();
        sc[tid] += t;
        __syncthreads();
    }
    int excl = sc[tid] - v;
    cur[tid] = excl;
    int i = b * 256 + tid;
    if (i < N) {
        nseg[i] = make_int2(b * CAP + excl, v);
        float dg = (float)(v + 1);
        dinv[i] = rsqrtf(dg);
        invd[i] = 1.0f / dg;
    }
    __syncthreads();
    for (int j = tid; j < cnt; j += 256) {
        int rec = src[j];
        int pos = atomicAdd(&cur[rec >> 20], 1);
        stage[pos] = rec & 0xFFFFF;
    }
    __syncthreads();
    int* dst = csr + b * CAP;
    for (int j = tid; j < cnt; j += 256) dst[j] = stage[j];
}

// cast+transpose W1[256][128] fp32 -> W1T[128][256] bf16
__global__ __launch_bounds__(256) void castW1_k(const float* __restrict__ W1, short* __restrict__ W1T) {
    int idx = blockIdx.x * 256 + threadIdx.x;     // 32768
    int k = idx >> 7, n = idx & 127;
    W1T[n * FIN + k] = f2bf(W1[idx]);
}

// cast+transpose W2[128][40] fp32 -> W2T[48][128] bf16, cols 40..47 zero
__global__ __launch_bounds__(256) void castW2_k(const float* __restrict__ W2, short* __restrict__ W2T) {
    int idx = blockIdx.x * 256 + threadIdx.x;     // 48*128 = 6144
    int c = idx >> 7, k = idx & 127;
    W2T[idx] = (c < CDIM) ? f2bf(W2[k * CDIM + c]) : (short)0;
}

// GEMM1 (MFMA bf16): T1b = bf16( X(Nx256) @ W1(256x128) ).
#define LDSTRIDE 40
__global__ __launch_bounds__(256) void gemm1_mfma_k(const float* __restrict__ X,
                                                    const short* __restrict__ W1T,
                                                    short* __restrict__ T1b, int N) {
    __shared__ short As[128 * LDSTRIDE];
    __shared__ short Bs[128 * LDSTRIDE];
    const int tid = threadIdx.x;
    const int lane = tid & 63;
    const int wid = tid >> 6;
    const int w0 = wid & 1, w1 = wid >> 1;
    const int quad = lane >> 4;
    const int l16 = lane & 15;
    const int rowbase = blockIdx.x * 128;
    const int sr = tid >> 1;
    const int sh = tid & 1;

    f32x4 acc[4][4];
#pragma unroll
    for (int a = 0; a < 4; a++)
#pragma unroll
        for (int b = 0; b < 4; b++) acc[a][b] = (f32x4){0.f, 0.f, 0.f, 0.f};

    const int arow = min(rowbase + sr, N - 1);
    const float* xsrc = X + (size_t)arow * FIN + sh * 16;
    const int4* bsrc = (const int4*)(W1T + (size_t)sr * FIN + sh * 16);

    for (int k0 = 0; k0 < FIN; k0 += 32) {
        float vals[16];
        *(float4*)&vals[0]  = *(const float4*)(xsrc + k0);
        *(float4*)&vals[4]  = *(const float4*)(xsrc + k0 + 4);
        *(float4*)&vals[8]  = *(const float4*)(xsrc + k0 + 8);
        *(float4*)&vals[12] = *(const float4*)(xsrc + k0 + 12);
        short tmp[16];
#pragma unroll
        for (int c = 0; c < 16; c++) tmp[c] = f2bf(vals[c]);
        ((int4*)&As[sr * LDSTRIDE + sh * 16])[0] = ((int4*)tmp)[0];
        ((int4*)&As[sr * LDSTRIDE + sh * 16])[1] = ((int4*)tmp)[1];
        int4 b0 = bsrc[k0 >> 3];
        int4 b1 = bsrc[(k0 >> 3) + 1];
        ((int4*)&Bs[sr * LDSTRIDE + sh * 16])[0] = b0;
        ((int4*)&Bs[sr * LDSTRIDE + sh * 16])[1] = b1;
        __syncthreads();

        bf16x8 afr[4], bfr[4];
#pragma unroll
        for (int mt = 0; mt < 4; mt++)
            afr[mt] = *(const bf16x8*)&As[(w1 * 64 + mt * 16 + l16) * LDSTRIDE + quad * 8];
#pragma unroll
        for (int nt = 0; nt < 4; nt++)
            bfr[nt] = *(const bf16x8*)&Bs[(w0 * 64 + nt * 16 + l16) * LDSTRIDE + quad * 8];
#pragma unroll
        for (int mt = 0; mt < 4; mt++)
#pragma unroll
            for (int nt = 0; nt < 4; nt++)
                acc[mt][nt] = __builtin_amdgcn_mfma_f32_16x16x32_bf16(afr[mt], bfr[nt], acc[mt][nt], 0, 0, 0);
        __syncthreads();
    }
#pragma unroll
    for (int mt = 0; mt < 4; mt++) {
#pragma unroll
        for (int r = 0; r < 4; r++) {
            int row = rowbase + w1 * 64 + mt * 16 + quad * 4 + r;
            if (row < N) {
#pragma unroll
                for (int nt = 0; nt < 4; nt++) {
                    int col = w0 * 64 + nt * 16 + l16;
                    T1b[(size_t)row * HDIM + col] = f2bf(acc[mt][nt][r]);
                }
            }
        }
    }
}

// agg1: wave/node. readlane broadcasts -> saddr gathers, unroll 8. h out bf16.
__global__ __launch_bounds__(256) void agg1_k(const short* __restrict__ T1b, const int2* __restrict__ nseg,
                                              const int* __restrict__ csr, const float* __restrict__ dinv,
                                              const float* __restrict__ invd, const float* __restrict__ b1,
                                              unsigned* __restrict__ Hb, int N) {
    const int lane = threadIdx.x & 63;
    const int i = blockIdx.x * 4 + (threadIdx.x >> 6);
    if (i >= N) return;
    const int2 sg = nseg[i];
    const int e0 = sg.x, deg = sg.y;
    int sv = 0; float wv = 0.f;
    if (lane < deg) { sv = csr[e0 + lane]; wv = dinv[sv]; }

    float accx = 0.f, accy = 0.f;
    const int dmain = deg < 64 ? deg : 64;
    const int d8 = dmain & ~7;
    const unsigned* rowp = (const unsigned*)T1b;
    int j = 0;
    for (; j < d8; j += 8) {
        int   s0 = rdl_i(sv, j),     s1 = rdl_i(sv, j + 1), s2 = rdl_i(sv, j + 2), s3 = rdl_i(sv, j + 3);
        int   s4 = rdl_i(sv, j + 4), s5 = rdl_i(sv, j + 5), s6 = rdl_i(sv, j + 6), s7 = rdl_i(sv, j + 7);
        float w0 = rdl_f(wv, j),     w1 = rdl_f(wv, j + 1), w2 = rdl_f(wv, j + 2), w3 = rdl_f(wv, j + 3);
        float w4 = rdl_f(wv, j + 4), w5 = rdl_f(wv, j + 5), w6 = rdl_f(wv, j + 6), w7 = rdl_f(wv, j + 7);
        unsigned r0 = rowp[(size_t)s0 * 64 + lane];
        unsigned r1 = rowp[(size_t)s1 * 64 + lane];
        unsigned r2 = rowp[(size_t)s2 * 64 + lane];
        unsigned r3 = rowp[(size_t)s3 * 64 + lane];
        unsigned r4 = rowp[(size_t)s4 * 64 + lane];
        unsigned r5 = rowp[(size_t)s5 * 64 + lane];
        unsigned r6 = rowp[(size_t)s6 * 64 + lane];
        unsigned r7 = rowp[(size_t)s7 * 64 + lane];
        accx += w0 * bflo(r0) + w1 * bflo(r1) + w2 * bflo(r2) + w3 * bflo(r3)
              + w4 * bflo(r4) + w5 * bflo(r5) + w6 * bflo(r6) + w7 * bflo(r7);
        accy += w0 * bfhi(r0) + w1 * bfhi(r1) + w2 * bfhi(r2) + w3 * bfhi(r3)
              + w4 * bfhi(r4) + w5 * bfhi(r5) + w6 * bfhi(r6) + w7 * bfhi(r7);
    }
    for (; j < dmain; ++j) {
        int s = rdl_i(sv, j); float w = rdl_f(wv, j);
        unsigned r = rowp[(size_t)s * 64 + lane];
        accx += w * bflo(r); accy += w * bfhi(r);
    }
    for (int e = e0 + 64; e < e0 + deg; ++e) {     // rare tail (deg > 64)
        int s = csr[e]; float w = dinv[s];
        unsigned r = rowp[(size_t)s * 64 + lane];
        accx += w * bflo(r); accy += w * bfhi(r);
    }
    const float di = dinv[i], sf = invd[i];
    unsigned rs = rowp[(size_t)i * 64 + lane];
    float2 bc = *(const float2*)(b1 + 2 * lane);
    float ox = fmaxf(bc.x + sf * bflo(rs) + di * accx, 0.f);
    float oy = fmaxf(bc.y + sf * bfhi(rs) + di * accy, 0.f);
    unsigned pk = ((unsigned)(unsigned short)f2bf(ox)) | (((unsigned)(unsigned short)f2bf(oy)) << 16);
    Hb[(size_t)i * 64 + lane] = pk;
}

// GEMM2 (MFMA bf16): t2 = H(Nx128 bf16) @ W2T(48x128 bf16)^T, fp32 out (cols<40).
__global__ __launch_bounds__(256) void gemm2_mfma_k(const short* __restrict__ Hb,
                                                    const short* __restrict__ W2T,
                                                    float* __restrict__ T2, int N) {
    __shared__ short As[128 * LDSTRIDE];
    __shared__ short Bs[48 * LDSTRIDE];
    const int tid = threadIdx.x;
    const int lane = tid & 63;
    const int wid = tid >> 6;
    const int quad = lane >> 4;
    const int l16 = lane & 15;
    const int rowbase = blockIdx.x * 128;
    const int sr = tid >> 1;
    const int sh = tid & 1;

    f32x4 acc[2][3];
#pragma unroll
    for (int a = 0; a < 2; a++)
#pragma unroll
        for (int b = 0; b < 3; b++) acc[a][b] = (f32x4){0.f, 0.f, 0.f, 0.f};

    const int arow = min(rowbase + sr, N - 1);
    const int4* asrc = (const int4*)(Hb + (size_t)arow * HDIM + sh * 16);
    const int br = tid >> 1, bh = tid & 1;   // for tid < 96
    const int4* bsrc = (const int4*)(W2T + br * HDIM + bh * 16);

    for (int k0 = 0; k0 < HDIM; k0 += 32) {
        int4 a0 = asrc[k0 >> 3];
        int4 a1 = asrc[(k0 >> 3) + 1];
        ((int4*)&As[sr * LDSTRIDE + sh * 16])[0] = a0;
        ((int4*)&As[sr * LDSTRIDE + sh * 16])[1] = a1;
        if (tid < 96) {
            int4 b0 = bsrc[k0 >> 3];
            int4 b1 = bsrc[(k0 >> 3) + 1];
            ((int4*)&Bs[br * LDSTRIDE + bh * 16])[0] = b0;
            ((int4*)&Bs[br * LDSTRIDE + bh * 16])[1] = b1;
        }
        __syncthreads();
        bf16x8 afr[2], bfr[3];
#pragma unroll
        for (int mt = 0; mt < 2; mt++)
            afr[mt] = *(const bf16x8*)&As[(wid * 32 + mt * 16 + l16) * LDSTRIDE + quad * 8];
#pragma unroll
        for (int nt = 0; nt < 3; nt++)
            bfr[nt] = *(const bf16x8*)&Bs[(nt * 16 + l16) * LDSTRIDE + quad * 8];
#pragma unroll
        for (int mt = 0; mt < 2; mt++)
#pragma unroll
            for (int nt = 0; nt < 3; nt++)
                acc[mt][nt] = __builtin_amdgcn_mfma_f32_16x16x32_bf16(afr[mt], bfr[nt], acc[mt][nt], 0, 0, 0);
        __syncthreads();
    }
#pragma unroll
    for (int mt = 0; mt < 2; mt++) {
#pragma unroll
        for (int r = 0; r < 4; r++) {
            int row = rowbase + wid * 32 + mt * 16 + quad * 4 + r;
            if (row < N) {
#pragma unroll
                for (int nt = 0; nt < 3; nt++) {
                    int col = nt * 16 + l16;
                    if (col < CDIM) T2[(size_t)row * CDIM + col] = acc[mt][nt][r];
                }
            }
        }
    }
}

// agg2: wave/node, fp32 t2 (160B rows), readlane + unroll 8.
__global__ __launch_bounds__(256) void agg2_k(const float* __restrict__ T2, const int2* __restrict__ nseg,
                                              const int* __restrict__ csr, const float* __restrict__ dinv,
                                              const float* __restrict__ invd, const float* __restrict__ b2,
                                              float* __restrict__ OUT, int N) {
    const int lane = threadIdx.x & 63;
    const int i = blockIdx.x * 4 + (threadIdx.x >> 6);
    if (i >= N) return;
    const int2 sg = nseg[i];
    const int e0 = sg.x, deg = sg.y;
    int sv = 0; float wv = 0.f;
    if (lane < deg) { sv = csr[e0 + lane]; wv = dinv[sv]; }
    const int c = lane < CDIM ? lane : CDIM - 1;
    float accE = 0.f;
    const int dmain = deg < 64 ? deg : 64;
    const int d8 = dmain & ~7;
    int j = 0;
    for (; j < d8; j += 8) {
        int   s0 = rdl_i(sv, j),     s1 = rdl_i(sv, j + 1), s2 = rdl_i(sv, j + 2), s3 = rdl_i(sv, j + 3);
        int   s4 = rdl_i(sv, j + 4), s5 = rdl_i(sv, j + 5), s6 = rdl_i(sv, j + 6), s7 = rdl_i(sv, j + 7);
        float w0 = rdl_f(wv, j),     w1 = rdl_f(wv, j + 1), w2 = rdl_f(wv, j + 2), w3 = rdl_f(wv, j + 3);
        float w4 = rdl_f(wv, j + 4), w5 = rdl_f(wv, j + 5), w6 = rdl_f(wv, j + 6), w7 = rdl_f(wv, j + 7);
        float v0 = T2[(size_t)s0 * CDIM + c];
        float v1 = T2[(size_t)s1 * CDIM + c];
        float v2 = T2[(size_t)s2 * CDIM + c];
        float v3 = T2[(size_t)s3 * CDIM + c];
        float v4 = T2[(size_t)s4 * CDIM + c];
        float v5 = T2[(size_t)s5 * CDIM + c];
        float v6 = T2[(size_t)s6 * CDIM + c];
        float v7 = T2[(size_t)s7 * CDIM + c];
        accE += w0 * v0 + w1 * v1 + w2 * v2 + w3 * v3 + w4 * v4 + w5 * v5 + w6 * v6 + w7 * v7;
    }
    for (; j < dmain; ++j) {
        int s = rdl_i(sv, j); float w = rdl_f(wv, j);
        accE += w * T2[(size_t)s * CDIM + c];
    }
    for (int e = e0 + 64; e < e0 + deg; ++e) {
        int s = csr[e]; float w = dinv[s];
        accE += w * T2[(size_t)s * CDIM + c];
    }
    if (lane < CDIM)
        OUT[(size_t)i * CDIM + lane] = b2[lane] + invd[i] * T2[(size_t)i * CDIM + lane] + dinv[i] * accE;
}

extern "C" void kernel_launch(void* const* d_in, const int* in_sizes, int n_in,
                              void* d_out, int out_size, void* d_ws, size_t ws_size,
                              hipStream_t stream) {
    const float* x   = (const float*)d_in[0];
    const int*   ei  = (const int*)d_in[1];     // int32 in harness
    const float* W1  = (const float*)d_in[2];
    const float* b1  = (const float*)d_in[3];
    const float* W2  = (const float*)d_in[4];
    const float* b2  = (const float*)d_in[5];
    float*       out = (float*)d_out;

    const int Hd  = in_sizes[3];            // 128
    const int Fin = in_sizes[2] / Hd;       // 256
    const int N   = in_sizes[0] / Fin;      // 100000
    const int E   = in_sizes[1] / 2;        // 1600000

    const int NBUCK = (N + 255) / 256;      // 391
    const int NB1   = (E + EC - 1) / EC;    // 196

    char* base = (char*)d_ws;
    size_t off = 0;
    auto alloc = [&](size_t bytes) -> void* {
        void* p = base + off;
        off += (bytes + 255) & ~(size_t)255;
        return p;
    };
    // region A: mat+bmem (pass1/2 only), overlaid later by t1b (gemm1 onward)
    size_t matB  = (size_t)NB1 * NBUCK * 4;
    size_t bmemB = (size_t)NBUCK * CAP * 4;
    size_t t1bB  = (size_t)N * HDIM * 2;
    size_t regA  = matB + 256 + bmemB;
    if (t1bB > regA) regA = t1bB;
    char* pA = (char*)alloc(regA);
    int*   mat  = (int*)pA;
    int*   bmem = (int*)(pA + ((matB + 255) & ~(size_t)255));
    short* t1b  = (short*)pA;

    int*      bcnt = (int*)alloc((size_t)NBUCK * 4);
    int*      csr  = (int*)alloc((size_t)NBUCK * CAP * 4);
    int2*     nseg = (int2*)alloc((size_t)N * 8);
    float*    dinv = (float*)alloc((size_t)N * 4);
    float*    invd = (float*)alloc((size_t)N * 4);
    short*    W1T  = (short*)alloc((size_t)HDIM * FIN * 2);
    short*    W2T  = (short*)alloc((size_t)48 * HDIM * 2);
    unsigned* hb   = (unsigned*)alloc((size_t)N * HDIM * 2);
    float*    t2   = (float*)alloc((size_t)N * CDIM * 4);

    p1_hist_k<<<NB1, 1024, 0, stream>>>(ei, mat, E, NBUCK);
    scan_cols_k<<<NBUCK, 64, 0, stream>>>(mat, bcnt, NB1, NBUCK);
    p1_scatter_k<<<NB1, 1024, 0, stream>>>(ei, mat, bmem, E, NBUCK);
    p2_build_k<<<NBUCK, 256, 0, stream>>>(bmem, bcnt, csr, nseg, dinv, invd, N);
    castW1_k<<<(HDIM * Fin + 255) / 256, 256, 0, stream>>>(W1, W1T);
    castW2_k<<<(48 * HDIM + 255) / 256, 256, 0, stream>>>(W2, W2T);

    gemm1_mfma_k<<<(N + 127) / 128, 256, 0, stream>>>(x, W1T, t1b, N);
    agg1_k<<<(N + 3) / 4, 256, 0, stream>>>(t1b, nseg, csr, dinv, invd, b1, hb, N);
    gemm2_mfma_k<<<(N + 127) / 128, 256, 0, stream>>>((const short*)hb, W2T, t2, N);
    agg2_k<<<(N + 3) / 4, 256, 0, stream>>>(t2, nseg, csr, dinv, invd, b2, out, N);
}

// Round 6
// 360.584 us; speedup vs baseline: 1.9224x; 1.0001x over previous
//
#include <hip/hip_runtime.h>
#include <hip/hip_bf16.h>

// GCN 2-layer. R6: agg kernels gather 4 rows per global_load_dwordx4
// (quad-per-neighbor layout + cross-quad butterfly), castW fused.

#define FIN 256
#define HDIM 128
#define CDIM 40
#define CAP 8192          // per-bucket edge capacity (mean 4096)
#define EC 8192           // edges per block in pass 1

typedef __attribute__((ext_vector_type(8))) short bf16x8;
typedef __attribute__((ext_vector_type(4))) float f32x4;

__device__ inline short f2bf(float f) {               // RNE fp32 -> bf16
    unsigned u = __float_as_uint(f);
    unsigned r = (u + 0x7FFFu + ((u >> 16) & 1u)) >> 16;
    return (short)r;
}
__device__ inline float bflo(unsigned u) { return __uint_as_float(u << 16); }
__device__ inline float bfhi(unsigned u) { return __uint_as_float(u & 0xFFFF0000u); }

// ---- pass 1a: per-block bucket histograms ----
__global__ __launch_bounds__(1024) void p1_hist_k(const int* __restrict__ ei, int* __restrict__ mat,
                                                  int E, int NBUCK) {
    __shared__ int hist[512];
    for (int t = threadIdx.x; t < NBUCK; t += 1024) hist[t] = 0;
    __syncthreads();
    int e0 = blockIdx.x * EC;
#pragma unroll
    for (int k = 0; k < EC; k += 1024) {
        int e = e0 + k + threadIdx.x;
        if (e < E) atomicAdd(&hist[ei[E + e] >> 8], 1);
    }
    __syncthreads();
    for (int t = threadIdx.x; t < NBUCK; t += 1024) mat[blockIdx.x * NBUCK + t] = hist[t];
}

// ---- pass 1b: column scan -> global write bases (in-place), bucket counts ----
__global__ __launch_bounds__(64) void scan_cols_k(int* __restrict__ mat, int* __restrict__ bcnt,
                                                  int NB1, int NBUCK) {
    int b = blockIdx.x;
    int lane = threadIdx.x;
    int carry = b * CAP;
    for (int c0 = 0; c0 < NB1; c0 += 64) {
        int idx = c0 + lane;
        int v = (idx < NB1) ? mat[idx * NBUCK + b] : 0;
        int incl = v;
#pragma unroll
        for (int off = 1; off < 64; off <<= 1) {
            int t = __shfl_up(incl, off);
            if (lane >= off) incl += t;
        }
        if (idx < NB1) mat[idx * NBUCK + b] = carry + (incl - v);
        carry += __shfl(incl, 63);
    }
    if (lane == 0) bcnt[b] = carry - b * CAP;
}

// ---- pass 1c: scatter packed records into bucket append regions ----
__global__ __launch_bounds__(1024) void p1_scatter_k(const int* __restrict__ ei, const int* __restrict__ mat,
                                                     int* __restrict__ bmem, int E, int NBUCK) {
    __shared__ int base[512];
    for (int t = threadIdx.x; t < NBUCK; t += 1024) base[t] = mat[blockIdx.x * NBUCK + t];
    __syncthreads();
    int e0 = blockIdx.x * EC;
#pragma unroll
    for (int k = 0; k < EC; k += 1024) {
        int e = e0 + k + threadIdx.x;
        if (e < E) {
            int s = ei[e];
            int d = ei[E + e];
            int pos = atomicAdd(&base[d >> 8], 1);
            bmem[pos] = s | ((d & 255) << 20);    // s < 2^20 (N=100000)
        }
    }
}

// ---- pass 2: per-bucket CSR build, coalesced writes ----
__global__ __launch_bounds__(256) void p2_build_k(const int* __restrict__ bmem, const int* __restrict__ bcnt,
                                                  int* __restrict__ csr, int2* __restrict__ nseg,
                                                  float* __restrict__ dinv, float* __restrict__ invd, int N) {
    __shared__ int hist[256], cur[256], sc[256];
    __shared__ int stage[CAP];
    const int b = blockIdx.x;
    const int tid = threadIdx.x;
    int cnt = bcnt[b];
    if (cnt > CAP) cnt = CAP;
    const int* src = bmem + b * CAP;
    hist[tid] = 0;
    __syncthreads();
    for (int j = tid; j < cnt; j += 256) atomicAdd(&hist[src[j] >> 20], 1);
    __syncthreads();
    int v = hist[tid];
    sc[tid] = v;
    __syncthreads();
    for (int off = 1; off < 256; off <<= 1) {
        int t = (tid >= off) ? sc[tid - off] : 0;
        __syncthreads();
        sc[tid] += t;
        __syncthreads();
    }
    int excl = sc[tid] - v;
    cur[tid] = excl;
    int i = b * 256 + tid;
    if (i < N) {
        nseg[i] = make_int2(b * CAP + excl, v);
        float dg = (float)(v + 1);
        dinv[i] = rsqrtf(dg);
        invd[i] = 1.0f / dg;
    }
    __syncthreads();
    for (int j = tid; j < cnt; j += 256) {
        int rec = src[j];
        int pos = atomicAdd(&cur[rec >> 20], 1);
        stage[pos] = rec & 0xFFFFF;
    }
    __syncthreads();
    int* dst = csr + b * CAP;
    for (int j = tid; j < cnt; j += 256) dst[j] = stage[j];
}

// fused weight cast: W1[256][128]->W1T[128][256] bf16; W2[128][40]->W2T[48][128] bf16 (pad 0)
__global__ __launch_bounds__(256) void castW_k(const float* __restrict__ W1, const float* __restrict__ W2,
                                               short* __restrict__ W1T, short* __restrict__ W2T) {
    int idx = blockIdx.x * 256 + threadIdx.x;
    if (idx < FIN * HDIM) {
        int k = idx >> 7, n = idx & 127;
        W1T[n * FIN + k] = f2bf(W1[idx]);
    } else {
        int j = idx - FIN * HDIM;
        if (j < 48 * HDIM) {
            int c = j >> 7, k = j & 127;
            W2T[j] = (c < CDIM) ? f2bf(W2[k * CDIM + c]) : (short)0;
        }
    }
}

// GEMM1 (MFMA bf16): T1b = bf16( X(Nx256) @ W1(256x128) ).
#define LDSTRIDE 40
__global__ __launch_bounds__(256) void gemm1_mfma_k(const float* __restrict__ X,
                                                    const short* __restrict__ W1T,
                                                    short* __restrict__ T1b, int N) {
    __shared__ short As[128 * LDSTRIDE];
    __shared__ short Bs[128 * LDSTRIDE];
    const int tid = threadIdx.x;
    const int lane = tid & 63;
    const int wid = tid >> 6;
    const int w0 = wid & 1, w1 = wid >> 1;
    const int quad = lane >> 4;
    const int l16 = lane & 15;
    const int rowbase = blockIdx.x * 128;
    const int sr = tid >> 1;
    const int sh = tid & 1;

    f32x4 acc[4][4];
#pragma unroll
    for (int a = 0; a < 4; a++)
#pragma unroll
        for (int b = 0; b < 4; b++) acc[a][b] = (f32x4){0.f, 0.f, 0.f, 0.f};

    const int arow = min(rowbase + sr, N - 1);
    const float* xsrc = X + (size_t)arow * FIN + sh * 16;
    const int4* bsrc = (const int4*)(W1T + (size_t)sr * FIN + sh * 16);

    for (int k0 = 0; k0 < FIN; k0 += 32) {
        float vals[16];
        *(float4*)&vals[0]  = *(const float4*)(xsrc + k0);
        *(float4*)&vals[4]  = *(const float4*)(xsrc + k0 + 4);
        *(float4*)&vals[8]  = *(const float4*)(xsrc + k0 + 8);
        *(float4*)&vals[12] = *(const float4*)(xsrc + k0 + 12);
        short tmp[16];
#pragma unroll
        for (int c = 0; c < 16; c++) tmp[c] = f2bf(vals[c]);
        ((int4*)&As[sr * LDSTRIDE + sh * 16])[0] = ((int4*)tmp)[0];
        ((int4*)&As[sr * LDSTRIDE + sh * 16])[1] = ((int4*)tmp)[1];
        int4 b0 = bsrc[k0 >> 3];
        int4 b1 = bsrc[(k0 >> 3) + 1];
        ((int4*)&Bs[sr * LDSTRIDE + sh * 16])[0] = b0;
        ((int4*)&Bs[sr * LDSTRIDE + sh * 16])[1] = b1;
        __syncthreads();

        bf16x8 afr[4], bfr[4];
#pragma unroll
        for (int mt = 0; mt < 4; mt++)
            afr[mt] = *(const bf16x8*)&As[(w1 * 64 + mt * 16 + l16) * LDSTRIDE + quad * 8];
#pragma unroll
        for (int nt = 0; nt < 4; nt++)
            bfr[nt] = *(const bf16x8*)&Bs[(w0 * 64 + nt * 16 + l16) * LDSTRIDE + quad * 8];
#pragma unroll
        for (int mt = 0; mt < 4; mt++)
#pragma unroll
            for (int nt = 0; nt < 4; nt++)
                acc[mt][nt] = __builtin_amdgcn_mfma_f32_16x16x32_bf16(afr[mt], bfr[nt], acc[mt][nt], 0, 0, 0);
        __syncthreads();
    }
#pragma unroll
    for (int mt = 0; mt < 4; mt++) {
#pragma unroll
        for (int r = 0; r < 4; r++) {
            int row = rowbase + w1 * 64 + mt * 16 + quad * 4 + r;
            if (row < N) {
#pragma unroll
                for (int nt = 0; nt < 4; nt++) {
                    int col = w0 * 64 + nt * 16 + l16;
                    T1b[(size_t)row * HDIM + col] = f2bf(acc[mt][nt][r]);
                }
            }
        }
    }
}

// agg1: wave/node. Quad-per-neighbor: one dwordx4 load fetches 4 rows/instr.
// lane = quad*16+ql; quad q handles neighbors j+q; lane covers cols ql*8..+7.
__global__ __launch_bounds__(256) void agg1_k(const short* __restrict__ T1b, const int2* __restrict__ nseg,
                                              const int* __restrict__ csr, const float* __restrict__ dinv,
                                              const float* __restrict__ invd, const float* __restrict__ b1,
                                              unsigned* __restrict__ Hb, int N) {
    const int lane = threadIdx.x & 63;
    const int quad = lane >> 4;
    const int ql = lane & 15;
    const int i = blockIdx.x * 4 + (threadIdx.x >> 6);
    if (i >= N) return;
    const int2 sg = nseg[i];
    const int e0 = sg.x, deg = sg.y;
    int sv = 0; float wv = 0.f;
    if (lane < deg) { sv = csr[e0 + lane]; wv = dinv[sv]; }

    const uint4* rowp = (const uint4*)T1b;   // 16 uint4 per 256B row
    float acc[8];
#pragma unroll
    for (int t = 0; t < 8; t++) acc[t] = 0.f;

    const int dmain = deg < 64 ? deg : 64;
    for (int j = 0; j < dmain; j += 4) {
        int idx = j + quad;
        int sj = __shfl(sv, idx);
        float wj = __shfl(wv, idx);
        wj = (idx < dmain) ? wj : 0.f;
        uint4 u = rowp[sj * 16 + ql];
        acc[0] += wj * bflo(u.x); acc[1] += wj * bfhi(u.x);
        acc[2] += wj * bflo(u.y); acc[3] += wj * bfhi(u.y);
        acc[4] += wj * bflo(u.z); acc[5] += wj * bfhi(u.z);
        acc[6] += wj * bflo(u.w); acc[7] += wj * bfhi(u.w);
    }
    const int eEnd = e0 + deg;
    for (int e = e0 + 64; e < eEnd; e += 4) {          // rare tail deg > 64
        int idx = e + quad;
        int cl = idx < eEnd ? idx : eEnd - 1;
        int sj = csr[cl];
        float wj = (idx < eEnd) ? dinv[sj] : 0.f;
        uint4 u = rowp[sj * 16 + ql];
        acc[0] += wj * bflo(u.x); acc[1] += wj * bfhi(u.x);
        acc[2] += wj * bflo(u.y); acc[3] += wj * bfhi(u.y);
        acc[4] += wj * bflo(u.z); acc[5] += wj * bfhi(u.z);
        acc[6] += wj * bflo(u.w); acc[7] += wj * bfhi(u.w);
    }
    // fold quads
#pragma unroll
    for (int t = 0; t < 8; t++) {
        acc[t] += __shfl_xor(acc[t], 16);
        acc[t] += __shfl_xor(acc[t], 32);
    }
    const float di = dinv[i], sf = invd[i];
    uint4 us = rowp[i * 16 + ql];
    float4 bA = *(const float4*)(b1 + ql * 8);
    float4 bB = *(const float4*)(b1 + ql * 8 + 4);
    float o0 = fmaxf(bA.x + sf * bflo(us.x) + di * acc[0], 0.f);
    float o1 = fmaxf(bA.y + sf * bfhi(us.x) + di * acc[1], 0.f);
    float o2 = fmaxf(bA.z + sf * bflo(us.y) + di * acc[2], 0.f);
    float o3 = fmaxf(bA.w + sf * bfhi(us.y) + di * acc[3], 0.f);
    float o4 = fmaxf(bB.x + sf * bflo(us.z) + di * acc[4], 0.f);
    float o5 = fmaxf(bB.y + sf * bfhi(us.z) + di * acc[5], 0.f);
    float o6 = fmaxf(bB.z + sf * bflo(us.w) + di * acc[6], 0.f);
    float o7 = fmaxf(bB.w + sf * bfhi(us.w) + di * acc[7], 0.f);
    uint4 pk;
    pk.x = ((unsigned)(unsigned short)f2bf(o0)) | (((unsigned)(unsigned short)f2bf(o1)) << 16);
    pk.y = ((unsigned)(unsigned short)f2bf(o2)) | (((unsigned)(unsigned short)f2bf(o3)) << 16);
    pk.z = ((unsigned)(unsigned short)f2bf(o4)) | (((unsigned)(unsigned short)f2bf(o5)) << 16);
    pk.w = ((unsigned)(unsigned short)f2bf(o6)) | (((unsigned)(unsigned short)f2bf(o7)) << 16);
    if (quad == 0) ((uint4*)(Hb + (size_t)i * 64))[ql] = pk;
}

// GEMM2 (MFMA bf16): t2 = H(Nx128 bf16) @ W2T(48x128 bf16)^T, fp32 out (cols<40).
__global__ __launch_bounds__(256) void gemm2_mfma_k(const short* __restrict__ Hb,
                                                    const short* __restrict__ W2T,
                                                    float* __restrict__ T2, int N) {
    __shared__ short As[128 * LDSTRIDE];
    __shared__ short Bs[48 * LDSTRIDE];
    const int tid = threadIdx.x;
    const int lane = tid & 63;
    const int wid = tid >> 6;
    const int quad = lane >> 4;
    const int l16 = lane & 15;
    const int rowbase = blockIdx.x * 128;
    const int sr = tid >> 1;
    const int sh = tid & 1;

    f32x4 acc[2][3];
#pragma unroll
    for (int a = 0; a < 2; a++)
#pragma unroll
        for (int b = 0; b < 3; b++) acc[a][b] = (f32x4){0.f, 0.f, 0.f, 0.f};

    const int arow = min(rowbase + sr, N - 1);
    const int4* asrc = (const int4*)(Hb + (size_t)arow * HDIM + sh * 16);
    const int br = tid >> 1, bh = tid & 1;   // for tid < 96
    const int4* bsrc = (const int4*)(W2T + br * HDIM + bh * 16);

    for (int k0 = 0; k0 < HDIM; k0 += 32) {
        int4 a0 = asrc[k0 >> 3];
        int4 a1 = asrc[(k0 >> 3) + 1];
        ((int4*)&As[sr * LDSTRIDE + sh * 16])[0] = a0;
        ((int4*)&As[sr * LDSTRIDE + sh * 16])[1] = a1;
        if (tid < 96) {
            int4 b0 = bsrc[k0 >> 3];
            int4 b1 = bsrc[(k0 >> 3) + 1];
            ((int4*)&Bs[br * LDSTRIDE + bh * 16])[0] = b0;
            ((int4*)&Bs[br * LDSTRIDE + bh * 16])[1] = b1;
        }
        __syncthreads();
        bf16x8 afr[2], bfr[3];
#pragma unroll
        for (int mt = 0; mt < 2; mt++)
            afr[mt] = *(const bf16x8*)&As[(wid * 32 + mt * 16 + l16) * LDSTRIDE + quad * 8];
#pragma unroll
        for (int nt = 0; nt < 3; nt++)
            bfr[nt] = *(const bf16x8*)&Bs[(nt * 16 + l16) * LDSTRIDE + quad * 8];
#pragma unroll
        for (int mt = 0; mt < 2; mt++)
#pragma unroll
            for (int nt = 0; nt < 3; nt++)
                acc[mt][nt] = __builtin_amdgcn_mfma_f32_16x16x32_bf16(afr[mt], bfr[nt], acc[mt][nt], 0, 0, 0);
        __syncthreads();
    }
#pragma unroll
    for (int mt = 0; mt < 2; mt++) {
#pragma unroll
        for (int r = 0; r < 4; r++) {
            int row = rowbase + wid * 32 + mt * 16 + quad * 4 + r;
            if (row < N) {
#pragma unroll
                for (int nt = 0; nt < 3; nt++) {
                    int col = nt * 16 + l16;
                    if (col < CDIM) T2[(size_t)row * CDIM + col] = acc[mt][nt][r];
                }
            }
        }
    }
}

// agg2: wave/node, fp32 160B rows = 10 dwordx4; quad-per-neighbor.
__global__ __launch_bounds__(256) void agg2_k(const float* __restrict__ T2, const int2* __restrict__ nseg,
                                              const int* __restrict__ csr, const float* __restrict__ dinv,
                                              const float* __restrict__ invd, const float* __restrict__ b2,
                                              float* __restrict__ OUT, int N) {
    const int lane = threadIdx.x & 63;
    const int quad = lane >> 4;
    const int qlr = lane & 15;
    const int ql = qlr < 10 ? qlr : 9;     // clamp (same line as ql=9: no extra traffic)
    const bool act = qlr < 10;
    const int i = blockIdx.x * 4 + (threadIdx.x >> 6);
    if (i >= N) return;
    const int2 sg = nseg[i];
    const int e0 = sg.x, deg = sg.y;
    int sv = 0; float wv = 0.f;
    if (lane < deg) { sv = csr[e0 + lane]; wv = dinv[sv]; }
    float acc[4] = {0.f, 0.f, 0.f, 0.f};
    const int dmain = deg < 64 ? deg : 64;
    for (int j = 0; j < dmain; j += 4) {
        int idx = j + quad;
        int sj = __shfl(sv, idx);
        float wj = __shfl(wv, idx);
        wj = (idx < dmain && act) ? wj : 0.f;
        float4 v = *(const float4*)(T2 + sj * CDIM + ql * 4);
        acc[0] += wj * v.x; acc[1] += wj * v.y; acc[2] += wj * v.z; acc[3] += wj * v.w;
    }
    const int eEnd = e0 + deg;
    for (int e = e0 + 64; e < eEnd; e += 4) {          // rare tail
        int idx = e + quad;
        int cl = idx < eEnd ? idx : eEnd - 1;
        int sj = csr[cl];
        float wj = (idx < eEnd && act) ? dinv[sj] : 0.f;
        float4 v = *(const float4*)(T2 + sj * CDIM + ql * 4);
        acc[0] += wj * v.x; acc[1] += wj * v.y; acc[2] += wj * v.z; acc[3] += wj * v.w;
    }
#pragma unroll
    for (int t = 0; t < 4; t++) {
        acc[t] += __shfl_xor(acc[t], 16);
        acc[t] += __shfl_xor(acc[t], 32);
    }
    const float di = dinv[i], sf = invd[i];
    float4 vs = *(const float4*)(T2 + (size_t)i * CDIM + ql * 4);
    float4 bb = *(const float4*)(b2 + ql * 4);
    float4 o;
    o.x = bb.x + sf * vs.x + di * acc[0];
    o.y = bb.y + sf * vs.y + di * acc[1];
    o.z = bb.z + sf * vs.z + di * acc[2];
    o.w = bb.w + sf * vs.w + di * acc[3];
    if (quad == 0 && act) *(float4*)(OUT + (size_t)i * CDIM + qlr * 4) = o;
}

extern "C" void kernel_launch(void* const* d_in, const int* in_sizes, int n_in,
                              void* d_out, int out_size, void* d_ws, size_t ws_size,
                              hipStream_t stream) {
    const float* x   = (const float*)d_in[0];
    const int*   ei  = (const int*)d_in[1];     // int32 in harness
    const float* W1  = (const float*)d_in[2];
    const float* b1  = (const float*)d_in[3];
    const float* W2  = (const float*)d_in[4];
    const float* b2  = (const float*)d_in[5];
    float*       out = (float*)d_out;

    const int Hd  = in_sizes[3];            // 128
    const int Fin = in_sizes[2] / Hd;       // 256
    const int N   = in_sizes[0] / Fin;      // 100000
    const int E   = in_sizes[1] / 2;        // 1600000

    const int NBUCK = (N + 255) / 256;      // 391
    const int NB1   = (E + EC - 1) / EC;    // 196

    char* base = (char*)d_ws;
    size_t off = 0;
    auto alloc = [&](size_t bytes) -> void* {
        void* p = base + off;
        off += (bytes + 255) & ~(size_t)255;
        return p;
    };
    // region A: mat+bmem (pass1/2 only), overlaid later by t1b (gemm1 onward)
    size_t matB  = (size_t)NB1 * NBUCK * 4;
    size_t bmemB = (size_t)NBUCK * CAP * 4;
    size_t t1bB  = (size_t)N * HDIM * 2;
    size_t regA  = matB + 256 + bmemB;
    if (t1bB > regA) regA = t1bB;
    char* pA = (char*)alloc(regA);
    int*   mat  = (int*)pA;
    int*   bmem = (int*)(pA + ((matB + 255) & ~(size_t)255));
    short* t1b  = (short*)pA;

    int*      bcnt = (int*)alloc((size_t)NBUCK * 4);
    int*      csr  = (int*)alloc((size_t)NBUCK * CAP * 4);
    int2*     nseg = (int2*)alloc((size_t)N * 8);
    float*    dinv = (float*)alloc((size_t)N * 4);
    float*    invd = (float*)alloc((size_t)N * 4);
    short*    W1T  = (short*)alloc((size_t)HDIM * FIN * 2);
    short*    W2T  = (short*)alloc((size_t)48 * HDIM * 2);
    unsigned* hb   = (unsigned*)alloc((size_t)N * HDIM * 2);
    float*    t2   = (float*)alloc((size_t)N * CDIM * 4);

    p1_hist_k<<<NB1, 1024, 0, stream>>>(ei, mat, E, NBUCK);
    scan_cols_k<<<NBUCK, 64, 0, stream>>>(mat, bcnt, NB1, NBUCK);
    p1_scatter_k<<<NB1, 1024, 0, stream>>>(ei, mat, bmem, E, NBUCK);
    p2_build_k<<<NBUCK, 256, 0, stream>>>(bmem, bcnt, csr, nseg, dinv, invd, N);
    castW_k<<<(FIN * HDIM + 48 * HDIM + 255) / 256, 256, 0, stream>>>(W1, W2, W1T, W2T);

    gemm1_mfma_k<<<(N + 127) / 128, 256, 0, stream>>>(x, W1T, t1b, N);
    agg1_k<<<(N + 3) / 4, 256, 0, stream>>>(t1b, nseg, csr, dinv, invd, b1, hb, N);
    gemm2_mfma_k<<<(N + 127) / 128, 256, 0, stream>>>((const short*)hb, W2T, t2, N);
    agg2_k<<<(N + 3) / 4, 256, 0, stream>>>(t2, nseg, csr, dinv, invd, b2, out, N);
}

// Round 7
// 338.677 us; speedup vs baseline: 2.0468x; 1.0647x over previous
//
#include <hip/hip_runtime.h>
#include <hip/hip_bf16.h>

// GCN 2-layer. R7: agg1 quad-gather unrolled x4 (4 row-loads in flight),
// t2 stored bf16 48-col rows, agg2 oct-gather (8 rows/load) unrolled x2.

#define FIN 256
#define HDIM 128
#define CDIM 40
#define CAP 8192          // per-bucket edge capacity (mean 4096)
#define EC 8192           // edges per block in pass 1

typedef __attribute__((ext_vector_type(8))) short bf16x8;
typedef __attribute__((ext_vector_type(4))) float f32x4;

__device__ inline short f2bf(float f) {               // RNE fp32 -> bf16
    unsigned u = __float_as_uint(f);
    unsigned r = (u + 0x7FFFu + ((u >> 16) & 1u)) >> 16;
    return (short)r;
}
__device__ inline float bflo(unsigned u) { return __uint_as_float(u << 16); }
__device__ inline float bfhi(unsigned u) { return __uint_as_float(u & 0xFFFF0000u); }

// ---- pass 1a: per-block bucket histograms ----
__global__ __launch_bounds__(1024) void p1_hist_k(const int* __restrict__ ei, int* __restrict__ mat,
                                                  int E, int NBUCK) {
    __shared__ int hist[512];
    for (int t = threadIdx.x; t < NBUCK; t += 1024) hist[t] = 0;
    __syncthreads();
    int e0 = blockIdx.x * EC;
#pragma unroll
    for (int k = 0; k < EC; k += 1024) {
        int e = e0 + k + threadIdx.x;
        if (e < E) atomicAdd(&hist[ei[E + e] >> 8], 1);
    }
    __syncthreads();
    for (int t = threadIdx.x; t < NBUCK; t += 1024) mat[blockIdx.x * NBUCK + t] = hist[t];
}

// ---- pass 1b: column scan -> global write bases (in-place), bucket counts ----
__global__ __launch_bounds__(64) void scan_cols_k(int* __restrict__ mat, int* __restrict__ bcnt,
                                                  int NB1, int NBUCK) {
    int b = blockIdx.x;
    int lane = threadIdx.x;
    int carry = b * CAP;
    for (int c0 = 0; c0 < NB1; c0 += 64) {
        int idx = c0 + lane;
        int v = (idx < NB1) ? mat[idx * NBUCK + b] : 0;
        int incl = v;
#pragma unroll
        for (int off = 1; off < 64; off <<= 1) {
            int t = __shfl_up(incl, off);
            if (lane >= off) incl += t;
        }
        if (idx < NB1) mat[idx * NBUCK + b] = carry + (incl - v);
        carry += __shfl(incl, 63);
    }
    if (lane == 0) bcnt[b] = carry - b * CAP;
}

// ---- pass 1c: scatter packed records into bucket append regions ----
__global__ __launch_bounds__(1024) void p1_scatter_k(const int* __restrict__ ei, const int* __restrict__ mat,
                                                     int* __restrict__ bmem, int E, int NBUCK) {
    __shared__ int base[512];
    for (int t = threadIdx.x; t < NBUCK; t += 1024) base[t] = mat[blockIdx.x * NBUCK + t];
    __syncthreads();
    int e0 = blockIdx.x * EC;
#pragma unroll
    for (int k = 0; k < EC; k += 1024) {
        int e = e0 + k + threadIdx.x;
        if (e < E) {
            int s = ei[e];
            int d = ei[E + e];
            int pos = atomicAdd(&base[d >> 8], 1);
            bmem[pos] = s | ((d & 255) << 20);    // s < 2^20 (N=100000)
        }
    }
}

// ---- pass 2: per-bucket CSR build, coalesced writes ----
__global__ __launch_bounds__(256) void p2_build_k(const int* __restrict__ bmem, const int* __restrict__ bcnt,
                                                  int* __restrict__ csr, int2* __restrict__ nseg,
                                                  float* __restrict__ dinv, float* __restrict__ invd, int N) {
    __shared__ int hist[256], cur[256], sc[256];
    __shared__ int stage[CAP];
    const int b = blockIdx.x;
    const int tid = threadIdx.x;
    int cnt = bcnt[b];
    if (cnt > CAP) cnt = CAP;
    const int* src = bmem + b * CAP;
    hist[tid] = 0;
    __syncthreads();
    for (int j = tid; j < cnt; j += 256) atomicAdd(&hist[src[j] >> 20], 1);
    __syncthreads();
    int v = hist[tid];
    sc[tid] = v;
    __syncthreads();
    for (int off = 1; off < 256; off <<= 1) {
        int t = (tid >= off) ? sc[tid - off] : 0;
        __syncthreads();
        sc[tid] += t;
        __syncthreads();
    }
    int excl = sc[tid] - v;
    cur[tid] = excl;
    int i = b * 256 + tid;
    if (i < N) {
        nseg[i] = make_int2(b * CAP + excl, v);
        float dg = (float)(v + 1);
        dinv[i] = rsqrtf(dg);
        invd[i] = 1.0f / dg;
    }
    __syncthreads();
    for (int j = tid; j < cnt; j += 256) {
        int rec = src[j];
        int pos = atomicAdd(&cur[rec >> 20], 1);
        stage[pos] = rec & 0xFFFFF;
    }
    __syncthreads();
    int* dst = csr + b * CAP;
    for (int j = tid; j < cnt; j += 256) dst[j] = stage[j];
}

// fused weight cast: W1[256][128]->W1T[128][256] bf16; W2[128][40]->W2T[48][128] bf16 (pad 0)
__global__ __launch_bounds__(256) void castW_k(const float* __restrict__ W1, const float* __restrict__ W2,
                                               short* __restrict__ W1T, short* __restrict__ W2T) {
    int idx = blockIdx.x * 256 + threadIdx.x;
    if (idx < FIN * HDIM) {
        int k = idx >> 7, n = idx & 127;
        W1T[n * FIN + k] = f2bf(W1[idx]);
    } else {
        int j = idx - FIN * HDIM;
        if (j < 48 * HDIM) {
            int c = j >> 7, k = j & 127;
            W2T[j] = (c < CDIM) ? f2bf(W2[k * CDIM + c]) : (short)0;
        }
    }
}

// GEMM1 (MFMA bf16): T1b = bf16( X(Nx256) @ W1(256x128) ).
#define LDSTRIDE 40
__global__ __launch_bounds__(256) void gemm1_mfma_k(const float* __restrict__ X,
                                                    const short* __restrict__ W1T,
                                                    short* __restrict__ T1b, int N) {
    __shared__ short As[128 * LDSTRIDE];
    __shared__ short Bs[128 * LDSTRIDE];
    const int tid = threadIdx.x;
    const int lane = tid & 63;
    const int wid = tid >> 6;
    const int w0 = wid & 1, w1 = wid >> 1;
    const int quad = lane >> 4;
    const int l16 = lane & 15;
    const int rowbase = blockIdx.x * 128;
    const int sr = tid >> 1;
    const int sh = tid & 1;

    f32x4 acc[4][4];
#pragma unroll
    for (int a = 0; a < 4; a++)
#pragma unroll
        for (int b = 0; b < 4; b++) acc[a][b] = (f32x4){0.f, 0.f, 0.f, 0.f};

    const int arow = min(rowbase + sr, N - 1);
    const float* xsrc = X + (size_t)arow * FIN + sh * 16;
    const int4* bsrc = (const int4*)(W1T + (size_t)sr * FIN + sh * 16);

    for (int k0 = 0; k0 < FIN; k0 += 32) {
        float vals[16];
        *(float4*)&vals[0]  = *(const float4*)(xsrc + k0);
        *(float4*)&vals[4]  = *(const float4*)(xsrc + k0 + 4);
        *(float4*)&vals[8]  = *(const float4*)(xsrc + k0 + 8);
        *(float4*)&vals[12] = *(const float4*)(xsrc + k0 + 12);
        short tmp[16];
#pragma unroll
        for (int c = 0; c < 16; c++) tmp[c] = f2bf(vals[c]);
        ((int4*)&As[sr * LDSTRIDE + sh * 16])[0] = ((int4*)tmp)[0];
        ((int4*)&As[sr * LDSTRIDE + sh * 16])[1] = ((int4*)tmp)[1];
        int4 b0 = bsrc[k0 >> 3];
        int4 b1 = bsrc[(k0 >> 3) + 1];
        ((int4*)&Bs[sr * LDSTRIDE + sh * 16])[0] = b0;
        ((int4*)&Bs[sr * LDSTRIDE + sh * 16])[1] = b1;
        __syncthreads();

        bf16x8 afr[4], bfr[4];
#pragma unroll
        for (int mt = 0; mt < 4; mt++)
            afr[mt] = *(const bf16x8*)&As[(w1 * 64 + mt * 16 + l16) * LDSTRIDE + quad * 8];
#pragma unroll
        for (int nt = 0; nt < 4; nt++)
            bfr[nt] = *(const bf16x8*)&Bs[(w0 * 64 + nt * 16 + l16) * LDSTRIDE + quad * 8];
#pragma unroll
        for (int mt = 0; mt < 4; mt++)
#pragma unroll
            for (int nt = 0; nt < 4; nt++)
                acc[mt][nt] = __builtin_amdgcn_mfma_f32_16x16x32_bf16(afr[mt], bfr[nt], acc[mt][nt], 0, 0, 0);
        __syncthreads();
    }
#pragma unroll
    for (int mt = 0; mt < 4; mt++) {
#pragma unroll
        for (int r = 0; r < 4; r++) {
            int row = rowbase + w1 * 64 + mt * 16 + quad * 4 + r;
            if (row < N) {
#pragma unroll
                for (int nt = 0; nt < 4; nt++) {
                    int col = w0 * 64 + nt * 16 + l16;
                    T1b[(size_t)row * HDIM + col] = f2bf(acc[mt][nt][r]);
                }
            }
        }
    }
}

// agg1: wave/node. Quad-per-neighbor gather (4 rows per dwordx4) UNROLLED x4:
// 16 edges/iter, 4 independent row-loads in flight. Masked so deg<16 takes 1 iter.
__global__ __launch_bounds__(256) void agg1_k(const short* __restrict__ T1b, const int2* __restrict__ nseg,
                                              const int* __restrict__ csr, const float* __restrict__ dinv,
                                              const float* __restrict__ invd, const float* __restrict__ b1,
                                              unsigned* __restrict__ Hb, int N) {
    const int lane = threadIdx.x & 63;
    const int quad = lane >> 4;
    const int ql = lane & 15;
    const int i = blockIdx.x * 4 + (threadIdx.x >> 6);
    if (i >= N) return;
    const int2 sg = nseg[i];
    const int e0 = sg.x, deg = sg.y;
    int sv = 0; float wv = 0.f;
    if (lane < deg) { sv = csr[e0 + lane]; wv = dinv[sv]; }

    const uint4* rowp = (const uint4*)T1b;   // 16 uint4 per 256B row
    float acc[8];
#pragma unroll
    for (int t = 0; t < 8; t++) acc[t] = 0.f;

    const int dmain = deg < 64 ? deg : 64;
    for (int j = 0; j < dmain; j += 16) {
        const int i0 = j + quad, i1 = j + 4 + quad, i2 = j + 8 + quad, i3 = j + 12 + quad;
        int s0 = __shfl(sv, i0); int s1 = __shfl(sv, i1);
        int s2 = __shfl(sv, i2); int s3 = __shfl(sv, i3);
        float w0 = __shfl(wv, i0); float w1 = __shfl(wv, i1);
        float w2 = __shfl(wv, i2); float w3 = __shfl(wv, i3);
        w0 = (i0 < dmain) ? w0 : 0.f;
        w1 = (i1 < dmain) ? w1 : 0.f;
        w2 = (i2 < dmain) ? w2 : 0.f;
        w3 = (i3 < dmain) ? w3 : 0.f;
        uint4 u0 = rowp[s0 * 16 + ql];
        uint4 u1 = rowp[s1 * 16 + ql];
        uint4 u2 = rowp[s2 * 16 + ql];
        uint4 u3 = rowp[s3 * 16 + ql];
        acc[0] += w0 * bflo(u0.x) + w1 * bflo(u1.x) + w2 * bflo(u2.x) + w3 * bflo(u3.x);
        acc[1] += w0 * bfhi(u0.x) + w1 * bfhi(u1.x) + w2 * bfhi(u2.x) + w3 * bfhi(u3.x);
        acc[2] += w0 * bflo(u0.y) + w1 * bflo(u1.y) + w2 * bflo(u2.y) + w3 * bflo(u3.y);
        acc[3] += w0 * bfhi(u0.y) + w1 * bfhi(u1.y) + w2 * bfhi(u2.y) + w3 * bfhi(u3.y);
        acc[4] += w0 * bflo(u0.z) + w1 * bflo(u1.z) + w2 * bflo(u2.z) + w3 * bflo(u3.z);
        acc[5] += w0 * bfhi(u0.z) + w1 * bfhi(u1.z) + w2 * bfhi(u2.z) + w3 * bfhi(u3.z);
        acc[6] += w0 * bflo(u0.w) + w1 * bflo(u1.w) + w2 * bflo(u2.w) + w3 * bflo(u3.w);
        acc[7] += w0 * bfhi(u0.w) + w1 * bfhi(u1.w) + w2 * bfhi(u2.w) + w3 * bfhi(u3.w);
    }
    const int eEnd = e0 + deg;
    for (int e = e0 + 64; e < eEnd; e += 4) {          // rare tail deg > 64
        int idx = e + quad;
        int cl = idx < eEnd ? idx : eEnd - 1;
        int sj = csr[cl];
        float wj = (idx < eEnd) ? dinv[sj] : 0.f;
        uint4 u = rowp[sj * 16 + ql];
        acc[0] += wj * bflo(u.x); acc[1] += wj * bfhi(u.x);
        acc[2] += wj * bflo(u.y); acc[3] += wj * bfhi(u.y);
        acc[4] += wj * bflo(u.z); acc[5] += wj * bfhi(u.z);
        acc[6] += wj * bflo(u.w); acc[7] += wj * bfhi(u.w);
    }
    // fold quads
#pragma unroll
    for (int t = 0; t < 8; t++) {
        acc[t] += __shfl_xor(acc[t], 16);
        acc[t] += __shfl_xor(acc[t], 32);
    }
    const float di = dinv[i], sf = invd[i];
    uint4 us = rowp[i * 16 + ql];
    float4 bA = *(const float4*)(b1 + ql * 8);
    float4 bB = *(const float4*)(b1 + ql * 8 + 4);
    float o0 = fmaxf(bA.x + sf * bflo(us.x) + di * acc[0], 0.f);
    float o1 = fmaxf(bA.y + sf * bfhi(us.x) + di * acc[1], 0.f);
    float o2 = fmaxf(bA.z + sf * bflo(us.y) + di * acc[2], 0.f);
    float o3 = fmaxf(bA.w + sf * bfhi(us.y) + di * acc[3], 0.f);
    float o4 = fmaxf(bB.x + sf * bflo(us.z) + di * acc[4], 0.f);
    float o5 = fmaxf(bB.y + sf * bfhi(us.z) + di * acc[5], 0.f);
    float o6 = fmaxf(bB.z + sf * bflo(us.w) + di * acc[6], 0.f);
    float o7 = fmaxf(bB.w + sf * bfhi(us.w) + di * acc[7], 0.f);
    uint4 pk;
    pk.x = ((unsigned)(unsigned short)f2bf(o0)) | (((unsigned)(unsigned short)f2bf(o1)) << 16);
    pk.y = ((unsigned)(unsigned short)f2bf(o2)) | (((unsigned)(unsigned short)f2bf(o3)) << 16);
    pk.z = ((unsigned)(unsigned short)f2bf(o4)) | (((unsigned)(unsigned short)f2bf(o5)) << 16);
    pk.w = ((unsigned)(unsigned short)f2bf(o6)) | (((unsigned)(unsigned short)f2bf(o7)) << 16);
    if (quad == 0) ((uint4*)(Hb + (size_t)i * 64))[ql] = pk;
}

// GEMM2 (MFMA bf16): T2b[N][48] bf16 = H(Nx128 bf16) @ W2T(48x128)^T. Pad cols 40-47 = 0.
__global__ __launch_bounds__(256) void gemm2_mfma_k(const short* __restrict__ Hb,
                                                    const short* __restrict__ W2T,
                                                    short* __restrict__ T2b, int N) {
    __shared__ short As[128 * LDSTRIDE];
    __shared__ short Bs[48 * LDSTRIDE];
    const int tid = threadIdx.x;
    const int lane = tid & 63;
    const int wid = tid >> 6;
    const int quad = lane >> 4;
    const int l16 = lane & 15;
    const int rowbase = blockIdx.x * 128;
    const int sr = tid >> 1;
    const int sh = tid & 1;

    f32x4 acc[2][3];
#pragma unroll
    for (int a = 0; a < 2; a++)
#pragma unroll
        for (int b = 0; b < 3; b++) acc[a][b] = (f32x4){0.f, 0.f, 0.f, 0.f};

    const int arow = min(rowbase + sr, N - 1);
    const int4* asrc = (const int4*)(Hb + (size_t)arow * HDIM + sh * 16);
    const int br = tid >> 1, bh = tid & 1;   // for tid < 96
    const int4* bsrc = (const int4*)(W2T + br * HDIM + bh * 16);

    for (int k0 = 0; k0 < HDIM; k0 += 32) {
        int4 a0 = asrc[k0 >> 3];
        int4 a1 = asrc[(k0 >> 3) + 1];
        ((int4*)&As[sr * LDSTRIDE + sh * 16])[0] = a0;
        ((int4*)&As[sr * LDSTRIDE + sh * 16])[1] = a1;
        if (tid < 96) {
            int4 b0 = bsrc[k0 >> 3];
            int4 b1 = bsrc[(k0 >> 3) + 1];
            ((int4*)&Bs[br * LDSTRIDE + bh * 16])[0] = b0;
            ((int4*)&Bs[br * LDSTRIDE + bh * 16])[1] = b1;
        }
        __syncthreads();
        bf16x8 afr[2], bfr[3];
#pragma unroll
        for (int mt = 0; mt < 2; mt++)
            afr[mt] = *(const bf16x8*)&As[(wid * 32 + mt * 16 + l16) * LDSTRIDE + quad * 8];
#pragma unroll
        for (int nt = 0; nt < 3; nt++)
            bfr[nt] = *(const bf16x8*)&Bs[(nt * 16 + l16) * LDSTRIDE + quad * 8];
#pragma unroll
        for (int mt = 0; mt < 2; mt++)
#pragma unroll
            for (int nt = 0; nt < 3; nt++)
                acc[mt][nt] = __builtin_amdgcn_mfma_f32_16x16x32_bf16(afr[mt], bfr[nt], acc[mt][nt], 0, 0, 0);
        __syncthreads();
    }
#pragma unroll
    for (int mt = 0; mt < 2; mt++) {
#pragma unroll
        for (int r = 0; r < 4; r++) {
            int row = rowbase + wid * 32 + mt * 16 + quad * 4 + r;
            if (row < N) {
#pragma unroll
                for (int nt = 0; nt < 3; nt++) {
                    int col = nt * 16 + l16;
                    T2b[(size_t)row * 48 + col] = f2bf(acc[mt][nt][r]);
                }
            }
        }
    }
}

// agg2: wave/node. bf16 96B rows: oct-per-neighbor (8 rows per dwordx4), unroll x2.
__global__ __launch_bounds__(256) void agg2_k(const short* __restrict__ T2b, const int2* __restrict__ nseg,
                                              const int* __restrict__ csr, const float* __restrict__ dinv,
                                              const float* __restrict__ invd, const float* __restrict__ b2,
                                              float* __restrict__ OUT, int N) {
    const int lane = threadIdx.x & 63;
    const int oct = lane >> 3;       // 0..7: neighbor slot
    const int olr = lane & 7;        // 0..7: col group
    const int ol = olr < 6 ? olr : 5;   // clamp (row = 6 uint4); same line as ol=5
    const bool act = olr < 6;
    const int i = blockIdx.x * 4 + (threadIdx.x >> 6);
    if (i >= N) return;
    const int2 sg = nseg[i];
    const int e0 = sg.x, deg = sg.y;
    int sv = 0; float wv = 0.f;
    if (lane < deg) { sv = csr[e0 + lane]; wv = dinv[sv]; }

    const uint4* rowp = (const uint4*)T2b;   // 6 uint4 per 96B row
    float acc[8];
#pragma unroll
    for (int t = 0; t < 8; t++) acc[t] = 0.f;

    const int dmain = deg < 64 ? deg : 64;
    for (int j = 0; j < dmain; j += 16) {
        const int i0 = j + oct, i1 = j + 8 + oct;
        int s0 = __shfl(sv, i0); int s1 = __shfl(sv, i1);
        float w0 = __shfl(wv, i0); float w1 = __shfl(wv, i1);
        w0 = (i0 < dmain && act) ? w0 : 0.f;
        w1 = (i1 < dmain && act) ? w1 : 0.f;
        uint4 u0 = rowp[s0 * 6 + ol];
        uint4 u1 = rowp[s1 * 6 + ol];
        acc[0] += w0 * bflo(u0.x) + w1 * bflo(u1.x);
        acc[1] += w0 * bfhi(u0.x) + w1 * bfhi(u1.x);
        acc[2] += w0 * bflo(u0.y) + w1 * bflo(u1.y);
        acc[3] += w0 * bfhi(u0.y) + w1 * bfhi(u1.y);
        acc[4] += w0 * bflo(u0.z) + w1 * bflo(u1.z);
        acc[5] += w0 * bfhi(u0.z) + w1 * bfhi(u1.z);
        acc[6] += w0 * bflo(u0.w) + w1 * bflo(u1.w);
        acc[7] += w0 * bfhi(u0.w) + w1 * bfhi(u1.w);
    }
    const int eEnd = e0 + deg;
    for (int e = e0 + 64; e < eEnd; e += 8) {          // rare tail
        int idx = e + oct;
        int cl = idx < eEnd ? idx : eEnd - 1;
        int sj = csr[cl];
        float wj = (idx < eEnd && act) ? dinv[sj] : 0.f;
        uint4 u = rowp[sj * 6 + ol];
        acc[0] += wj * bflo(u.x); acc[1] += wj * bfhi(u.x);
        acc[2] += wj * bflo(u.y); acc[3] += wj * bfhi(u.y);
        acc[4] += wj * bflo(u.z); acc[5] += wj * bfhi(u.z);
        acc[6] += wj * bflo(u.w); acc[7] += wj * bfhi(u.w);
    }
    // fold octs (same olr across octs)
#pragma unroll
    for (int t = 0; t < 8; t++) {
        acc[t] += __shfl_xor(acc[t], 8);
        acc[t] += __shfl_xor(acc[t], 16);
        acc[t] += __shfl_xor(acc[t], 32);
    }
    if (oct == 0 && olr < 5) {        // cols olr*8..+7, all < 40
        const float di = dinv[i], sf = invd[i];
        uint4 us = rowp[i * 6 + olr];
        float4 bA = *(const float4*)(b2 + olr * 8);
        float4 bB = *(const float4*)(b2 + olr * 8 + 4);
        float4 oA, oB;
        oA.x = bA.x + sf * bflo(us.x) + di * acc[0];
        oA.y = bA.y + sf * bfhi(us.x) + di * acc[1];
        oA.z = bA.z + sf * bflo(us.y) + di * acc[2];
        oA.w = bA.w + sf * bfhi(us.y) + di * acc[3];
        oB.x = bB.x + sf * bflo(us.z) + di * acc[4];
        oB.y = bB.y + sf * bfhi(us.z) + di * acc[5];
        oB.z = bB.z + sf * bflo(us.w) + di * acc[6];
        oB.w = bB.w + sf * bfhi(us.w) + di * acc[7];
        *(float4*)(OUT + (size_t)i * CDIM + olr * 8) = oA;
        *(float4*)(OUT + (size_t)i * CDIM + olr * 8 + 4) = oB;
    }
}

extern "C" void kernel_launch(void* const* d_in, const int* in_sizes, int n_in,
                              void* d_out, int out_size, void* d_ws, size_t ws_size,
                              hipStream_t stream) {
    const float* x   = (const float*)d_in[0];
    const int*   ei  = (const int*)d_in[1];     // int32 in harness
    const float* W1  = (const float*)d_in[2];
    const float* b1  = (const float*)d_in[3];
    const float* W2  = (const float*)d_in[4];
    const float* b2  = (const float*)d_in[5];
    float*       out = (float*)d_out;

    const int Hd  = in_sizes[3];            // 128
    const int Fin = in_sizes[2] / Hd;       // 256
    const int N   = in_sizes[0] / Fin;      // 100000
    const int E   = in_sizes[1] / 2;        // 1600000

    const int NBUCK = (N + 255) / 256;      // 391
    const int NB1   = (E + EC - 1) / EC;    // 196

    char* base = (char*)d_ws;
    size_t off = 0;
    auto alloc = [&](size_t bytes) -> void* {
        void* p = base + off;
        off += (bytes + 255) & ~(size_t)255;
        return p;
    };
    // region A: mat+bmem (pass1/2 only), overlaid later by t1b (gemm1 onward)
    size_t matB  = (size_t)NB1 * NBUCK * 4;
    size_t bmemB = (size_t)NBUCK * CAP * 4;
    size_t t1bB  = (size_t)N * HDIM * 2;
    size_t regA  = matB + 256 + bmemB;
    if (t1bB > regA) regA = t1bB;
    char* pA = (char*)alloc(regA);
    int*   mat  = (int*)pA;
    int*   bmem = (int*)(pA + ((matB + 255) & ~(size_t)255));
    short* t1b  = (short*)pA;

    int*      bcnt = (int*)alloc((size_t)NBUCK * 4);
    int*      csr  = (int*)alloc((size_t)NBUCK * CAP * 4);
    int2*     nseg = (int2*)alloc((size_t)N * 8);
    float*    dinv = (float*)alloc((size_t)N * 4);
    float*    invd = (float*)alloc((size_t)N * 4);
    short*    W1T  = (short*)alloc((size_t)HDIM * FIN * 2);
    short*    W2T  = (short*)alloc((size_t)48 * HDIM * 2);
    unsigned* hb   = (unsigned*)alloc((size_t)N * HDIM * 2);
    short*    t2b  = (short*)alloc((size_t)N * 48 * 2);

    p1_hist_k<<<NB1, 1024, 0, stream>>>(ei, mat, E, NBUCK);
    scan_cols_k<<<NBUCK, 64, 0, stream>>>(mat, bcnt, NB1, NBUCK);
    p1_scatter_k<<<NB1, 1024, 0, stream>>>(ei, mat, bmem, E, NBUCK);
    p2_build_k<<<NBUCK, 256, 0, stream>>>(bmem, bcnt, csr, nseg, dinv, invd, N);
    castW_k<<<(FIN * HDIM + 48 * HDIM + 255) / 256, 256, 0, stream>>>(W1, W2, W1T, W2T);

    gemm1_mfma_k<<<(N + 127) / 128, 256, 0, stream>>>(x, W1T, t1b, N);
    agg1_k<<<(N + 3) / 4, 256, 0, stream>>>(t1b, nseg, csr, dinv, invd, b1, hb, N);
    gemm2_mfma_k<<<(N + 127) / 128, 256, 0, stream>>>((const short*)hb, W2T, t2b, N);
    agg2_k<<<(N + 3) / 4, 256, 0, stream>>>(t2b, nseg, csr, dinv, invd, b2, out, N);
}